// Round 1
// baseline (1769.692 us; speedup 1.0000x reference)
//
#include <hip/hip_runtime.h>

#define LEAKY(v) ((v) >= 0.f ? (v) : 0.2f*(v))

static const int B_ = 16;
static const int N_ = 1024;
static const int P_ = 16384;   // B*N
static const int KNN = 20;

// ---------------- prep: W2 = [wA ; wB - wA], bias2 = [0 ; b] ----------------
__global__ void prep_w2(const float* __restrict__ w, const float* __restrict__ b,
                        float* __restrict__ W2, float* __restrict__ bias2, int O, int C) {
    int i = blockIdx.x * 256 + threadIdx.x;
    int total = 2 * O * C;
    if (i < total) {
        int row = i / C, c = i % C;
        float val;
        if (row < O) val = w[row * 2 * C + c];
        else { int o = row - O; val = w[o * 2 * C + C + c] - w[o * 2 * C + c]; }
        W2[i] = val;
    }
    if (i < 2 * O) bias2[i] = (i < O) ? 0.f : b[i - O];
}

// ---------------- squared norms ----------------
__global__ void sqnorm(const float* __restrict__ x, int lda, int C, float* __restrict__ xx) {
    int p = blockIdx.x * 256 + threadIdx.x;
    if (p < P_) {
        const float* r = x + (size_t)p * lda;
        float s = 0.f;
        for (int c = 0; c < C; c++) s += r[c] * r[c];
        xx[p] = s;
    }
}

// ---------------- neg squared distance matrix: 2*dot - xx_n - xx_m ----------
__global__ void dist_kernel(const float* __restrict__ x, int lda, int C,
                            const float* __restrict__ xx, float* __restrict__ dist) {
    __shared__ float As[16][68];
    __shared__ float Bs[16][68];
    int b = blockIdx.z;
    int n0 = blockIdx.y * 64, m0 = blockIdx.x * 64;
    const float* xb = x + (size_t)b * N_ * lda;
    int tid = threadIdx.x;
    int tx = tid & 15, ty = tid >> 4;
    float acc[4][4] = {};
    for (int k0 = 0; k0 < C; k0 += 16) {
        for (int l = tid; l < 1024; l += 256) {
            int r = l >> 4, kk = l & 15, kg = k0 + kk;
            As[kk][r] = (kg < C) ? xb[(size_t)(n0 + r) * lda + kg] : 0.f;
            Bs[kk][r] = (kg < C) ? xb[(size_t)(m0 + r) * lda + kg] : 0.f;
        }
        __syncthreads();
        #pragma unroll
        for (int kk = 0; kk < 16; kk++) {
            float4 a4 = *(const float4*)&As[kk][ty * 4];
            float4 w4 = *(const float4*)&Bs[kk][tx * 4];
            float a[4] = {a4.x, a4.y, a4.z, a4.w};
            float w[4] = {w4.x, w4.y, w4.z, w4.w};
            #pragma unroll
            for (int i = 0; i < 4; i++)
                #pragma unroll
                for (int j = 0; j < 4; j++) acc[i][j] += a[i] * w[j];
        }
        __syncthreads();
    }
    for (int i = 0; i < 4; i++) {
        int n = n0 + ty * 4 + i;
        float xn = xx[b * N_ + n];
        for (int j = 0; j < 4; j++) {
            int m = m0 + tx * 4 + j;
            dist[((size_t)b * N_ + n) * N_ + m] = 2.f * acc[i][j] - xn - xx[b * N_ + m];
        }
    }
}

// ---------------- top-k=20 (largest) per row; one wave per row --------------
__global__ void topk_kernel(const float* __restrict__ dist, int* __restrict__ idx) {
    int wave = (blockIdx.x * 256 + threadIdx.x) >> 6;
    int lane = threadIdx.x & 63;
    if (wave >= P_) return;
    const float* row = dist + (size_t)wave * N_;
    float d[16];
    #pragma unroll
    for (int j = 0; j < 16; j++) d[j] = row[j * 64 + lane];
    int* out = idx + (size_t)wave * KNN;
    for (int it = 0; it < KNN; it++) {
        float bv = d[0]; int bj = 0;
        #pragma unroll
        for (int j = 1; j < 16; j++) if (d[j] > bv) { bv = d[j]; bj = j; }
        int bm = bj * 64 + lane;
        #pragma unroll
        for (int off = 32; off > 0; off >>= 1) {
            float ov = __shfl_xor(bv, off, 64);
            int   om = __shfl_xor(bm, off, 64);
            if (ov > bv || (ov == bv && om < bm)) { bv = ov; bm = om; }
        }
        if (lane == 0) out[it] = bm;
        if ((bm & 63) == lane) d[bm >> 6] = -3.4e38f;
    }
}

// ---------------- generic GEMM: out[m][n] = dot(A[m,:], W[n,:]) + bias[n] ---
__global__ void gemm_wt(const float* __restrict__ A, int lda,
                        const float* __restrict__ W, int ldw,
                        const float* __restrict__ bias,
                        float* __restrict__ out, int ldo, int K) {
    __shared__ float As[16][68];
    __shared__ float Ws[16][68];
    int m0 = blockIdx.y * 64, n0 = blockIdx.x * 64;
    int tid = threadIdx.x;
    int tx = tid & 15, ty = tid >> 4;
    float acc[4][4] = {};
    for (int k0 = 0; k0 < K; k0 += 16) {
        for (int l = tid; l < 1024; l += 256) {
            int r = l >> 4, kk = l & 15, kg = k0 + kk;
            As[kk][r] = (kg < K) ? A[(size_t)(m0 + r) * lda + kg] : 0.f;
            Ws[kk][r] = (kg < K) ? W[(size_t)(n0 + r) * ldw + kg] : 0.f;
        }
        __syncthreads();
        #pragma unroll
        for (int kk = 0; kk < 16; kk++) {
            float4 a4 = *(const float4*)&As[kk][ty * 4];
            float4 w4 = *(const float4*)&Ws[kk][tx * 4];
            float a[4] = {a4.x, a4.y, a4.z, a4.w};
            float w[4] = {w4.x, w4.y, w4.z, w4.w};
            #pragma unroll
            for (int i = 0; i < 4; i++)
                #pragma unroll
                for (int j = 0; j < 4; j++) acc[i][j] += a[i] * w[j];
        }
        __syncthreads();
    }
    for (int i = 0; i < 4; i++) {
        int m = m0 + ty * 4 + i;
        for (int j = 0; j < 4; j++) {
            int n = n0 + tx * 4 + j;
            out[(size_t)m * ldo + n] = acc[i][j] + bias[n];
        }
    }
}

// ---------------- gather neighbors, per-(p,o) max/min, per-channel stats ----
__global__ void gather_stats(const float* __restrict__ uv, const int* __restrict__ idx, int O,
                             float* __restrict__ ymax, float* __restrict__ ymin,
                             double* __restrict__ part, int ppb) {
    __shared__ double sd[256], sd2[256];
    int t = threadIdx.x;
    int R = 256 / O;           // O in {64,128,256}
    int o = t % O;
    int q = t / O;
    double s = 0.0, s2 = 0.0;
    int p0 = blockIdx.x * ppb;
    int ld = 2 * O;
    for (int lp = q; lp < ppb; lp += R) {
        int p = p0 + lp;
        int b = p >> 10;
        const int* ir = idx + (size_t)p * KNN;
        float v = uv[(size_t)p * ld + O + o];
        float mx = -3.4e38f, mn = 3.4e38f;
        for (int kk = 0; kk < KNN; kk++) {
            int j = ir[kk];
            float u = uv[((size_t)((b << 10) + j)) * ld + o];
            float y = u + v;
            mx = fmaxf(mx, y); mn = fminf(mn, y);
            s += (double)y; s2 += (double)y * (double)y;
        }
        ymax[(size_t)p * O + o] = mx;
        ymin[(size_t)p * O + o] = mn;
    }
    sd[t] = s; sd2[t] = s2;
    __syncthreads();
    if (t < O) {
        double a = 0.0, a2 = 0.0;
        for (int qq = 0; qq < R; qq++) { a += sd[qq * O + t]; a2 += sd2[qq * O + t]; }
        part[(size_t)blockIdx.x * O + t] = a;
        part[(size_t)gridDim.x * O + (size_t)blockIdx.x * O + t] = a2;
    }
}

// ---------------- per-channel column stats for final conv -------------------
__global__ void colstats(const float* __restrict__ h, int O, int ppb, double* __restrict__ part) {
    int t = threadIdx.x;
    int CPT = O / 256;         // 4 for O=1024
    double s[4] = {0, 0, 0, 0}, s2[4] = {0, 0, 0, 0};
    int p0 = blockIdx.x * ppb;
    for (int lp = 0; lp < ppb; lp++) {
        const float* row = h + (size_t)(p0 + lp) * O;
        for (int j = 0; j < CPT; j++) {
            float y = row[j * 256 + t];
            s[j] += (double)y; s2[j] += (double)y * (double)y;
        }
    }
    for (int j = 0; j < CPT; j++) {
        part[(size_t)blockIdx.x * O + j * 256 + t] = s[j];
        part[(size_t)gridDim.x * O + (size_t)blockIdx.x * O + j * 256 + t] = s2[j];
    }
}

// ---------------- reduce partials -> scale/shift ----------------------------
__global__ void finalize_stats(const double* __restrict__ part, int NB, int O,
                               const float* __restrict__ g, const float* __restrict__ bt,
                               float* __restrict__ scale, float* __restrict__ shift, double invCount) {
    int o = threadIdx.x;
    if (o >= O) return;
    double s = 0.0, s2 = 0.0;
    for (int b = 0; b < NB; b++) {
        s  += part[(size_t)b * O + o];
        s2 += part[(size_t)NB * O + (size_t)b * O + o];
    }
    double mean = s * invCount;
    double var = s2 * invCount - mean * mean;
    if (var < 0.0) var = 0.0;
    float sc = (float)(1.0 / sqrt(var + 1e-5)) * g[o];
    scale[o] = sc;
    shift[o] = bt[o] - (float)mean * sc;
}

// ---------------- edge conv epilogue: BN + leaky + (max over k done) --------
__global__ void apply_edge(const float* __restrict__ ymax, const float* __restrict__ ymin,
                           const float* __restrict__ scale, const float* __restrict__ shift,
                           float* __restrict__ xcat, int O, int off) {
    int i = blockIdx.x * 256 + threadIdx.x;
    if (i < P_ * O) {
        int p = i / O, o = i % O;
        float sc = scale[o];
        float y = (sc >= 0.f) ? ymax[i] : ymin[i];
        float val = y * sc + shift[o];
        xcat[(size_t)p * 512 + off + o] = LEAKY(val);
    }
}

// ---------------- global max+mean pool with fused BN+leaky ------------------
__global__ void pool_kernel(const float* __restrict__ h, const float* __restrict__ scale,
                            const float* __restrict__ shift, float* __restrict__ pooled) {
    int b = blockIdx.x;
    int o = blockIdx.y * 256 + threadIdx.x;   // O = 1024
    float sc = scale[o], sh = shift[o];
    float mx = -3.4e38f;
    double sm = 0.0;
    for (int n = 0; n < N_; n++) {
        float y = h[((size_t)b * N_ + n) * 1024 + o] * sc + sh;
        y = LEAKY(y);
        mx = fmaxf(mx, y);
        sm += (double)y;
    }
    pooled[(size_t)b * 2048 + o] = mx;
    pooled[(size_t)b * 2048 + 1024 + o] = (float)(sm * (1.0 / N_));
}

// ---------------- small FC: one wave per output -----------------------------
__global__ void fc_kernel(const float* __restrict__ in, int ldi,
                          const float* __restrict__ w, int ldw,
                          const float* __restrict__ bias,
                          float* __restrict__ out, int M, int Nn, int K) {
    int gw = (blockIdx.x * 256 + threadIdx.x) >> 6;
    int lane = threadIdx.x & 63;
    if (gw >= M * Nn) return;
    int m = gw / Nn, n = gw % Nn;
    const float* a = in + (size_t)m * ldi;
    const float* ww = w + (size_t)n * ldw;
    float s = 0.f;
    for (int kk = lane; kk < K; kk += 64) s += a[kk] * ww[kk];
    #pragma unroll
    for (int off = 32; off > 0; off >>= 1) s += __shfl_xor(s, off, 64);
    if (lane == 0) out[(size_t)m * Nn + n] = s + bias[n];
}

// ---------------- BN over batch axis (M=16) + leaky, in place ---------------
__global__ void bn_rows(float* __restrict__ z, int M, int O,
                        const float* __restrict__ g, const float* __restrict__ bt) {
    int o = blockIdx.x * 256 + threadIdx.x;
    if (o >= O) return;
    double s = 0.0, s2 = 0.0;
    for (int m = 0; m < M; m++) {
        float y = z[(size_t)m * O + o];
        s += (double)y; s2 += (double)y * (double)y;
    }
    double mean = s / M;
    double var = s2 / M - mean * mean;
    if (var < 0.0) var = 0.0;
    float sc = (float)(1.0 / sqrt(var + 1e-5)) * g[o];
    float sh = bt[o] - (float)mean * sc;
    for (int m = 0; m < M; m++) {
        float y = z[(size_t)m * O + o] * sc + sh;
        z[(size_t)m * O + o] = LEAKY(y);
    }
}

extern "C" void kernel_launch(void* const* d_in, const int* in_sizes, int n_in,
                              void* d_out, int out_size, void* d_ws, size_t ws_size,
                              hipStream_t stream) {
    const float* cloud = (const float*)d_in[0];
    // weights per edge layer: w,b,g,bt at indices 1+4L..4+4L
    const float* wf  = (const float*)d_in[17];
    const float* bf  = (const float*)d_in[18];
    const float* gf  = (const float*)d_in[19];
    const float* btf = (const float*)d_in[20];
    const float* wl1 = (const float*)d_in[21];
    const float* bl1 = (const float*)d_in[22];
    const float* gl1 = (const float*)d_in[23];
    const float* btl1= (const float*)d_in[24];
    const float* wl2 = (const float*)d_in[25];
    const float* bl2 = (const float*)d_in[26];
    const float* gl2 = (const float*)d_in[27];
    const float* btl2= (const float*)d_in[28];
    const float* wl3 = (const float*)d_in[29];
    const float* bl3 = (const float*)d_in[30];

    // workspace layout (bytes)
    const size_t OFF_XCAT  = 0;                        // 16384*512*4   = 33554432
    const size_t OFF_UV    = 33554432;                 // 16384*512*4   = 33554432
    const size_t OFF_YMAX  = 67108864;                 // 16384*256*4   = 16777216
    const size_t OFF_YMIN  = 83886080;                 // 16777216
    const size_t OFF_DIST  = 100663296;                // 16*1024*1024*4= 67108864 (aliased as hraw)
    const size_t OFF_IDX   = 167772160;                // 16384*20*4    = 1310720
    const size_t OFF_XX    = 169082880;                // 65536
    const size_t OFF_W2    = 169148416;                // 524288
    const size_t OFF_BIAS2 = 169672704;                // 4096
    const size_t OFF_PART  = 169676800;                // 4194304 (doubles)
    const size_t OFF_SCALE = 173871104;                // 4096
    const size_t OFF_SHIFT = 173875200;                // 4096
    const size_t OFF_POOL  = 173879296;                // 131072
    const size_t OFF_Z1    = 174010368;                // 32768
    const size_t OFF_Z2    = 174043136;                // 16384
    const size_t TOTAL     = 174059520;
    if (ws_size < TOTAL) return;  // insufficient scratch; avoid corruption

    char* ws = (char*)d_ws;
    float* xcat  = (float*)(ws + OFF_XCAT);
    float* uv    = (float*)(ws + OFF_UV);
    float* ymax  = (float*)(ws + OFF_YMAX);
    float* ymin  = (float*)(ws + OFF_YMIN);
    float* dist  = (float*)(ws + OFF_DIST);
    float* hraw  = (float*)(ws + OFF_DIST);   // alias, used after edge layers
    int*   idx   = (int*)  (ws + OFF_IDX);
    float* xx    = (float*)(ws + OFF_XX);
    float* W2    = (float*)(ws + OFF_W2);
    float* bias2 = (float*)(ws + OFF_BIAS2);
    double* part = (double*)(ws + OFF_PART);
    float* scale = (float*)(ws + OFF_SCALE);
    float* shift = (float*)(ws + OFF_SHIFT);
    float* pooled= (float*)(ws + OFF_POOL);
    float* z1    = (float*)(ws + OFF_Z1);
    float* z2    = (float*)(ws + OFF_Z2);

    const int Cs[4]   = {3, 64, 64, 128};
    const int Os[4]   = {64, 64, 128, 256};
    const int offs[4] = {0, 64, 128, 256};

    for (int L = 0; L < 4; L++) {
        int C = Cs[L], O = Os[L];
        const float* w  = (const float*)d_in[1 + 4 * L];
        const float* b  = (const float*)d_in[2 + 4 * L];
        const float* g  = (const float*)d_in[3 + 4 * L];
        const float* bt = (const float*)d_in[4 + 4 * L];
        const float* x  = (L == 0) ? cloud : (xcat + offs[L - 1]);
        int lda = (L == 0) ? 3 : 512;

        prep_w2<<<(2 * O * C + 255) / 256, 256, 0, stream>>>(w, b, W2, bias2, O, C);
        sqnorm<<<(P_ + 255) / 256, 256, 0, stream>>>(x, lda, C, xx);
        dist_kernel<<<dim3(16, 16, 16), 256, 0, stream>>>(x, lda, C, xx, dist);
        topk_kernel<<<(P_ * 64) / 256, 256, 0, stream>>>(dist, idx);
        gemm_wt<<<dim3(2 * O / 64, P_ / 64), 256, 0, stream>>>(x, lda, W2, C, bias2, uv, 2 * O, C);
        gather_stats<<<256, 256, 0, stream>>>(uv, idx, O, ymax, ymin, part, 64);
        finalize_stats<<<1, O, 0, stream>>>(part, 256, O, g, bt, scale, shift, 1.0 / ((double)P_ * KNN));
        apply_edge<<<(P_ * O + 255) / 256, 256, 0, stream>>>(ymax, ymin, scale, shift, xcat, O, offs[L]);
    }

    // final 1x1 conv: (16384 x 512) @ wf(1024 x 512)^T -> hraw (16384 x 1024)
    gemm_wt<<<dim3(1024 / 64, P_ / 64), 256, 0, stream>>>(xcat, 512, wf, 512, bf, hraw, 1024, 512);
    colstats<<<256, 256, 0, stream>>>(hraw, 1024, 64, part);
    finalize_stats<<<1, 1024, 0, stream>>>(part, 256, 1024, gf, btf, scale, shift, 1.0 / (double)P_);
    pool_kernel<<<dim3(16, 4), 256, 0, stream>>>(hraw, scale, shift, pooled);

    // MLP head
    fc_kernel<<<(16 * 512 * 64) / 256, 256, 0, stream>>>(pooled, 2048, wl1, 2048, bl1, z1, 16, 512, 2048);
    bn_rows<<<2, 256, 0, stream>>>(z1, 16, 512, gl1, btl1);
    fc_kernel<<<(16 * 256 * 64) / 256, 256, 0, stream>>>(z1, 512, wl2, 512, bl2, z2, 16, 256, 512);
    bn_rows<<<1, 256, 0, stream>>>(z2, 16, 256, gl2, btl2);
    fc_kernel<<<(16 * 40 * 64 + 255) / 256, 256, 0, stream>>>(z2, 256, wl3, 256, bl3, (float*)d_out, 16, 40, 256);
}

// Round 2
// 1324.847 us; speedup vs baseline: 1.3358x; 1.3358x over previous
//
#include <hip/hip_runtime.h>

#define LEAKY(v) ((v) >= 0.f ? (v) : 0.2f*(v))

static const int B_ = 16;
static const int N_ = 1024;
static const int P_ = 16384;   // B*N
static const int KNN = 20;

typedef __attribute__((ext_vector_type(8))) short short8v;
typedef __attribute__((ext_vector_type(4))) float f32x4;

__device__ inline ushort f2bf(float f) {
    unsigned u = __float_as_uint(f);
    unsigned r = u + 0x7FFFu + ((u >> 16) & 1u);
    return (ushort)(r >> 16);
}
__device__ inline float bf2f(ushort h) {
    return __uint_as_float(((unsigned)h) << 16);
}

// ---------------- prep: W2 = [wA ; wB - wA], bias2 = [0 ; b] ----------------
__global__ void prep_w2(const float* __restrict__ w, const float* __restrict__ b,
                        float* __restrict__ W2, float* __restrict__ bias2, int O, int C) {
    int i = blockIdx.x * 256 + threadIdx.x;
    int total = 2 * O * C;
    if (i < total) {
        int row = i / C, c = i % C;
        float val;
        if (row < O) val = w[row * 2 * C + c];
        else { int o = row - O; val = w[o * 2 * C + C + c] - w[o * 2 * C + c]; }
        W2[i] = val;
    }
    if (i < 2 * O) bias2[i] = (i < O) ? 0.f : b[i - O];
}

// ---------------- squared norms ----------------
__global__ void sqnorm(const float* __restrict__ x, int lda, int C, float* __restrict__ xx) {
    int p = blockIdx.x * 256 + threadIdx.x;
    if (p < P_) {
        const float* r = x + (size_t)p * lda;
        float s = 0.f;
        for (int c = 0; c < C; c++) s += r[c] * r[c];
        xx[p] = s;
    }
}

// ---------------- neg squared distance matrix: 2*dot - xx_n - xx_m ----------
__global__ void dist_kernel(const float* __restrict__ x, int lda, int C,
                            const float* __restrict__ xx, float* __restrict__ dist) {
    __shared__ float As[16][68];
    __shared__ float Bs[16][68];
    int b = blockIdx.z;
    int n0 = blockIdx.y * 64, m0 = blockIdx.x * 64;
    const float* xb = x + (size_t)b * N_ * lda;
    int tid = threadIdx.x;
    int tx = tid & 15, ty = tid >> 4;
    float acc[4][4] = {};
    for (int k0 = 0; k0 < C; k0 += 16) {
        for (int l = tid; l < 1024; l += 256) {
            int r = l >> 4, kk = l & 15, kg = k0 + kk;
            As[kk][r] = (kg < C) ? xb[(size_t)(n0 + r) * lda + kg] : 0.f;
            Bs[kk][r] = (kg < C) ? xb[(size_t)(m0 + r) * lda + kg] : 0.f;
        }
        __syncthreads();
        #pragma unroll
        for (int kk = 0; kk < 16; kk++) {
            float4 a4 = *(const float4*)&As[kk][ty * 4];
            float4 w4 = *(const float4*)&Bs[kk][tx * 4];
            float a[4] = {a4.x, a4.y, a4.z, a4.w};
            float w[4] = {w4.x, w4.y, w4.z, w4.w};
            #pragma unroll
            for (int i = 0; i < 4; i++)
                #pragma unroll
                for (int j = 0; j < 4; j++) acc[i][j] += a[i] * w[j];
        }
        __syncthreads();
    }
    for (int i = 0; i < 4; i++) {
        int n = n0 + ty * 4 + i;
        float xn = xx[b * N_ + n];
        for (int j = 0; j < 4; j++) {
            int m = m0 + tx * 4 + j;
            dist[((size_t)b * N_ + n) * N_ + m] = 2.f * acc[i][j] - xn - xx[b * N_ + m];
        }
    }
}

// ---------------- top-k=20 (largest) per row; one wave per row --------------
__global__ void topk_kernel(const float* __restrict__ dist, int* __restrict__ idx) {
    int wave = (blockIdx.x * 256 + threadIdx.x) >> 6;
    int lane = threadIdx.x & 63;
    if (wave >= P_) return;
    const float* row = dist + (size_t)wave * N_;
    float d[16];
    #pragma unroll
    for (int j = 0; j < 16; j++) d[j] = row[j * 64 + lane];
    int* out = idx + (size_t)wave * KNN;
    for (int it = 0; it < KNN; it++) {
        float bv = d[0]; int bj = 0;
        #pragma unroll
        for (int j = 1; j < 16; j++) if (d[j] > bv) { bv = d[j]; bj = j; }
        int bm = bj * 64 + lane;
        #pragma unroll
        for (int off = 32; off > 0; off >>= 1) {
            float ov = __shfl_xor(bv, off, 64);
            int   om = __shfl_xor(bm, off, 64);
            if (ov > bv || (ov == bv && om < bm)) { bv = ov; bm = om; }
        }
        if (lane == 0) out[it] = bm;
        if ((bm & 63) == lane) d[bm >> 6] = -3.4e38f;
    }
}

// ---------------- generic fp32 GEMM: out[m][n] = dot(A[m,:], W[n,:]) + bias[n]
__global__ void gemm_wt(const float* __restrict__ A, int lda,
                        const float* __restrict__ W, int ldw,
                        const float* __restrict__ bias,
                        float* __restrict__ out, int ldo, int K) {
    __shared__ float As[16][68];
    __shared__ float Ws[16][68];
    int m0 = blockIdx.y * 64, n0 = blockIdx.x * 64;
    int tid = threadIdx.x;
    int tx = tid & 15, ty = tid >> 4;
    float acc[4][4] = {};
    for (int k0 = 0; k0 < K; k0 += 16) {
        for (int l = tid; l < 1024; l += 256) {
            int r = l >> 4, kk = l & 15, kg = k0 + kk;
            As[kk][r] = (kg < K) ? A[(size_t)(m0 + r) * lda + kg] : 0.f;
            Ws[kk][r] = (kg < K) ? W[(size_t)(n0 + r) * ldw + kg] : 0.f;
        }
        __syncthreads();
        #pragma unroll
        for (int kk = 0; kk < 16; kk++) {
            float4 a4 = *(const float4*)&As[kk][ty * 4];
            float4 w4 = *(const float4*)&Ws[kk][tx * 4];
            float a[4] = {a4.x, a4.y, a4.z, a4.w};
            float w[4] = {w4.x, w4.y, w4.z, w4.w};
            #pragma unroll
            for (int i = 0; i < 4; i++)
                #pragma unroll
                for (int j = 0; j < 4; j++) acc[i][j] += a[i] * w[j];
        }
        __syncthreads();
    }
    for (int i = 0; i < 4; i++) {
        int m = m0 + ty * 4 + i;
        for (int j = 0; j < 4; j++) {
            int n = n0 + tx * 4 + j;
            out[(size_t)m * ldo + n] = acc[i][j] + bias[n];
        }
    }
}

// ---------------- split fp32 -> [hi | hi | lo] bf16 rows (A2: P_ x 1536) ----
__global__ void convert_a2(const float* __restrict__ xcat, ushort* __restrict__ A2) {
    int i = blockIdx.x * 256 + threadIdx.x;       // P_*128 threads, 4 elems each
    int p = i >> 7, c = (i & 127) * 4;
    float4 v = *(const float4*)(xcat + (size_t)p * 512 + c);
    ushort4 h, l;
    h.x = f2bf(v.x); l.x = f2bf(v.x - bf2f(h.x));
    h.y = f2bf(v.y); l.y = f2bf(v.y - bf2f(h.y));
    h.z = f2bf(v.z); l.z = f2bf(v.z - bf2f(h.z));
    h.w = f2bf(v.w); l.w = f2bf(v.w - bf2f(h.w));
    ushort* row = A2 + (size_t)p * 1536 + c;
    *(ushort4*)(row) = h;
    *(ushort4*)(row + 512) = h;
    *(ushort4*)(row + 1024) = l;
}

// ---------------- split wf -> [hi | lo | hi] bf16 rows (B2: 1024 x 1536) ----
__global__ void convert_b2(const float* __restrict__ wf, ushort* __restrict__ B2) {
    int i = blockIdx.x * 256 + threadIdx.x;       // 1024*128 threads, 4 elems each
    int n = i >> 7, c = (i & 127) * 4;
    float4 v = *(const float4*)(wf + (size_t)n * 512 + c);
    ushort4 h, l;
    h.x = f2bf(v.x); l.x = f2bf(v.x - bf2f(h.x));
    h.y = f2bf(v.y); l.y = f2bf(v.y - bf2f(h.y));
    h.z = f2bf(v.z); l.z = f2bf(v.z - bf2f(h.z));
    h.w = f2bf(v.w); l.w = f2bf(v.w - bf2f(h.w));
    ushort* row = B2 + (size_t)n * 1536 + c;
    *(ushort4*)(row) = h;
    *(ushort4*)(row + 512) = l;
    *(ushort4*)(row + 1024) = h;
}

// ---------------- bf16 MFMA GEMM: out(16384x1024) = A2(16384x1536) @ B2^T ---
// 128x128 tile, BK=64, 4 waves (2x2), each wave 64x64 out, 16x16x32 MFMA.
// LDS XOR-swizzled (G4) so frag ds_read_b128 is ~conflict-free.
__global__ __launch_bounds__(256, 2)
void gemm_bf16(const ushort* __restrict__ A, const ushort* __restrict__ Bw,
               float* __restrict__ out) {
    const int K = 1536, Nn = 1024;
    __shared__ ushort lA[128 * 64];
    __shared__ ushort lB[128 * 64];
    int tid = threadIdx.x;
    int lane = tid & 63;
    int wid = tid >> 6;
    int wr = wid >> 1, wc = wid & 1;
    int m0 = blockIdx.y * 128, n0 = blockIdx.x * 128;

    f32x4 acc[4][4] = {};

    const ushort* pA = A + (size_t)m0 * K;
    const ushort* pB = Bw + (size_t)n0 * K;
    int rowu = tid >> 3, kcu = (tid & 7) * 8;

    short8v ra[4], rb[4];
    #pragma unroll
    for (int j = 0; j < 4; j++) {
        int row = rowu + j * 32;
        ra[j] = *(const short8v*)(pA + (size_t)row * K + kcu);
        rb[j] = *(const short8v*)(pB + (size_t)row * K + kcu);
    }

    for (int kt = 0; kt < 24; kt++) {
        __syncthreads();
        #pragma unroll
        for (int j = 0; j < 4; j++) {
            int row = rowu + j * 32;
            int off = (row * 128 + kcu * 2) ^ ((row & 7) << 4);
            *(short8v*)((char*)lA + off) = ra[j];
            *(short8v*)((char*)lB + off) = rb[j];
        }
        __syncthreads();
        if (kt < 23) {
            int kbase = (kt + 1) * 64 + kcu;
            #pragma unroll
            for (int j = 0; j < 4; j++) {
                int row = rowu + j * 32;
                ra[j] = *(const short8v*)(pA + (size_t)row * K + kbase);
                rb[j] = *(const short8v*)(pB + (size_t)row * K + kbase);
            }
        }
        #pragma unroll
        for (int ks = 0; ks < 2; ks++) {
            short8v af[4], bg[4];
            int kb2 = (ks * 32 + ((lane >> 4) << 3)) * 2;
            #pragma unroll
            for (int mb = 0; mb < 4; mb++) {
                int row = wr * 64 + mb * 16 + (lane & 15);
                int off = (row * 128 + kb2) ^ ((row & 7) << 4);
                af[mb] = *(const short8v*)((const char*)lA + off);
            }
            #pragma unroll
            for (int nb = 0; nb < 4; nb++) {
                int row = wc * 64 + nb * 16 + (lane & 15);
                int off = (row * 128 + kb2) ^ ((row & 7) << 4);
                bg[nb] = *(const short8v*)((const char*)lB + off);
            }
            #pragma unroll
            for (int mb = 0; mb < 4; mb++)
                #pragma unroll
                for (int nb = 0; nb < 4; nb++)
                    acc[mb][nb] = __builtin_amdgcn_mfma_f32_16x16x32_bf16(af[mb], bg[nb], acc[mb][nb], 0, 0, 0);
        }
    }

    int rbase = m0 + wr * 64 + ((lane >> 4) << 2);
    int cbase = n0 + wc * 64 + (lane & 15);
    #pragma unroll
    for (int mb = 0; mb < 4; mb++)
        #pragma unroll
        for (int nb = 0; nb < 4; nb++)
            #pragma unroll
            for (int r = 0; r < 4; r++)
                out[(size_t)(rbase + mb * 16 + r) * Nn + cbase + nb * 16] = acc[mb][nb][r];
}

// ---------------- gather neighbors, per-(p,o) max/min, per-channel stats ----
__global__ void gather_stats(const float* __restrict__ uv, const int* __restrict__ idx, int O,
                             float* __restrict__ ymax, float* __restrict__ ymin,
                             double* __restrict__ part, int ppb) {
    __shared__ double sd[256], sd2[256];
    int t = threadIdx.x;
    int R = 256 / O;           // O in {64,128,256}
    int o = t % O;
    int q = t / O;
    double s = 0.0, s2 = 0.0;
    int p0 = blockIdx.x * ppb;
    int ld = 2 * O;
    for (int lp = q; lp < ppb; lp += R) {
        int p = p0 + lp;
        int b = p >> 10;
        const int* ir = idx + (size_t)p * KNN;
        float v = uv[(size_t)p * ld + O + o];
        float mx = -3.4e38f, mn = 3.4e38f;
        for (int kk = 0; kk < KNN; kk++) {
            int j = ir[kk];
            float u = uv[((size_t)((b << 10) + j)) * ld + o];
            float y = u + v;
            mx = fmaxf(mx, y); mn = fminf(mn, y);
            s += (double)y; s2 += (double)y * (double)y;
        }
        ymax[(size_t)p * O + o] = mx;
        ymin[(size_t)p * O + o] = mn;
    }
    sd[t] = s; sd2[t] = s2;
    __syncthreads();
    if (t < O) {
        double a = 0.0, a2 = 0.0;
        for (int qq = 0; qq < R; qq++) { a += sd[qq * O + t]; a2 += sd2[qq * O + t]; }
        part[(size_t)blockIdx.x * O + t] = a;
        part[(size_t)gridDim.x * O + (size_t)blockIdx.x * O + t] = a2;
    }
}

// ---------------- per-channel column stats for final conv -------------------
__global__ void colstats(const float* __restrict__ h, int O, int ppb, double* __restrict__ part) {
    int t = threadIdx.x;
    int CPT = O / 256;         // 4 for O=1024
    double s[4] = {0, 0, 0, 0}, s2[4] = {0, 0, 0, 0};
    int p0 = blockIdx.x * ppb;
    for (int lp = 0; lp < ppb; lp++) {
        const float* row = h + (size_t)(p0 + lp) * O;
        for (int j = 0; j < CPT; j++) {
            float y = row[j * 256 + t];
            s[j] += (double)y; s2[j] += (double)y * (double)y;
        }
    }
    for (int j = 0; j < CPT; j++) {
        part[(size_t)blockIdx.x * O + j * 256 + t] = s[j];
        part[(size_t)gridDim.x * O + (size_t)blockIdx.x * O + j * 256 + t] = s2[j];
    }
}

// ---------------- reduce partials -> scale/shift (multi-block: O/64 blocks) -
__global__ void finalize_stats(const double* __restrict__ part, int NB, int O,
                               const float* __restrict__ g, const float* __restrict__ bt,
                               float* __restrict__ scale, float* __restrict__ shift, double invCount) {
    __shared__ double sa[256], sb2[256];
    int t = threadIdx.x;
    int o = blockIdx.x * 64 + (t & 63);
    int q = t >> 6;
    double s = 0.0, s2 = 0.0;
    for (int b = q; b < NB; b += 4) {
        s  += part[(size_t)b * O + o];
        s2 += part[(size_t)NB * O + (size_t)b * O + o];
    }
    sa[t] = s; sb2[t] = s2;
    __syncthreads();
    if (t < 64) {
        for (int c = 1; c < 4; c++) { s += sa[c * 64 + t]; s2 += sb2[c * 64 + t]; }
        double mean = s * invCount;
        double var = s2 * invCount - mean * mean;
        if (var < 0.0) var = 0.0;
        float sc = (float)(1.0 / sqrt(var + 1e-5)) * g[o];
        scale[o] = sc;
        shift[o] = bt[o] - (float)mean * sc;
    }
}

// ---------------- edge conv epilogue: BN + leaky (max over k done) ----------
__global__ void apply_edge(const float* __restrict__ ymax, const float* __restrict__ ymin,
                           const float* __restrict__ scale, const float* __restrict__ shift,
                           float* __restrict__ xcat, int O, int off) {
    int i = blockIdx.x * 256 + threadIdx.x;
    if (i < P_ * O) {
        int p = i / O, o = i % O;
        float sc = scale[o];
        float y = (sc >= 0.f) ? ymax[i] : ymin[i];
        float val = y * sc + shift[o];
        xcat[(size_t)p * 512 + off + o] = LEAKY(val);
    }
}

// ---------------- global max+mean pool with fused BN+leaky ------------------
// grid (16 b, 16 o-groups); 4 n-chunks of 256 per block, LDS combine.
__global__ void pool_kernel(const float* __restrict__ h, const float* __restrict__ scale,
                            const float* __restrict__ shift, float* __restrict__ pooled) {
    __shared__ float smax[256];
    __shared__ double ssum[256];
    int b = blockIdx.x, og = blockIdx.y;
    int t = threadIdx.x;
    int o = og * 64 + (t & 63);
    int ch = t >> 6;
    float sc = scale[o], sh = shift[o];
    float mx = -3.4e38f;
    double sm = 0.0;
    for (int n = ch * 256; n < ch * 256 + 256; n++) {
        float y = h[((size_t)b * N_ + n) * 1024 + o] * sc + sh;
        y = LEAKY(y);
        mx = fmaxf(mx, y);
        sm += (double)y;
    }
    smax[t] = mx; ssum[t] = sm;
    __syncthreads();
    if (t < 64) {
        for (int c = 1; c < 4; c++) { mx = fmaxf(mx, smax[c * 64 + t]); sm += ssum[c * 64 + t]; }
        pooled[(size_t)b * 2048 + o] = mx;
        pooled[(size_t)b * 2048 + 1024 + o] = (float)(sm * (1.0 / N_));
    }
}

// ---------------- small FC: one wave per output -----------------------------
__global__ void fc_kernel(const float* __restrict__ in, int ldi,
                          const float* __restrict__ w, int ldw,
                          const float* __restrict__ bias,
                          float* __restrict__ out, int M, int Nn, int K) {
    int gw = (blockIdx.x * 256 + threadIdx.x) >> 6;
    int lane = threadIdx.x & 63;
    if (gw >= M * Nn) return;
    int m = gw / Nn, n = gw % Nn;
    const float* a = in + (size_t)m * ldi;
    const float* ww = w + (size_t)n * ldw;
    float s = 0.f;
    for (int kk = lane; kk < K; kk += 64) s += a[kk] * ww[kk];
    #pragma unroll
    for (int off = 32; off > 0; off >>= 1) s += __shfl_xor(s, off, 64);
    if (lane == 0) out[(size_t)m * Nn + n] = s + bias[n];
}

// ---------------- BN over batch axis (M=16) + leaky, in place ---------------
__global__ void bn_rows(float* __restrict__ z, int M, int O,
                        const float* __restrict__ g, const float* __restrict__ bt) {
    int o = blockIdx.x * 256 + threadIdx.x;
    if (o >= O) return;
    double s = 0.0, s2 = 0.0;
    for (int m = 0; m < M; m++) {
        float y = z[(size_t)m * O + o];
        s += (double)y; s2 += (double)y * (double)y;
    }
    double mean = s / M;
    double var = s2 / M - mean * mean;
    if (var < 0.0) var = 0.0;
    float sc = (float)(1.0 / sqrt(var + 1e-5)) * g[o];
    float sh = bt[o] - (float)mean * sc;
    for (int m = 0; m < M; m++) {
        float y = z[(size_t)m * O + o] * sc + sh;
        z[(size_t)m * O + o] = LEAKY(y);
    }
}

extern "C" void kernel_launch(void* const* d_in, const int* in_sizes, int n_in,
                              void* d_out, int out_size, void* d_ws, size_t ws_size,
                              hipStream_t stream) {
    const float* cloud = (const float*)d_in[0];
    const float* wf  = (const float*)d_in[17];
    const float* gf  = (const float*)d_in[19];
    const float* btf = (const float*)d_in[20];
    const float* wl1 = (const float*)d_in[21];
    const float* bl1 = (const float*)d_in[22];
    const float* gl1 = (const float*)d_in[23];
    const float* btl1= (const float*)d_in[24];
    const float* wl2 = (const float*)d_in[25];
    const float* bl2 = (const float*)d_in[26];
    const float* gl2 = (const float*)d_in[27];
    const float* btl2= (const float*)d_in[28];
    const float* wl3 = (const float*)d_in[29];
    const float* bl3 = (const float*)d_in[30];

    // workspace layout (bytes)
    const size_t OFF_XCAT  = 0;                        // 33554432
    const size_t OFF_UV    = 33554432;                 // 33554432 (A2 aliases UV+YMAX+YMIN = 48MB)
    const size_t OFF_YMAX  = 67108864;                 // 16777216
    const size_t OFF_YMIN  = 83886080;                 // 16777216 (B2 aliases here)
    const size_t OFF_DIST  = 100663296;                // 67108864 (aliased as hraw)
    const size_t OFF_IDX   = 167772160;                // 1310720
    const size_t OFF_XX    = 169082880;                // 65536
    const size_t OFF_W2    = 169148416;                // 524288
    const size_t OFF_BIAS2 = 169672704;                // 4096
    const size_t OFF_PART  = 169676800;                // 4194304 (doubles)
    const size_t OFF_SCALE = 173871104;                // 4096
    const size_t OFF_SHIFT = 173875200;                // 4096
    const size_t OFF_POOL  = 173879296;                // 131072
    const size_t OFF_Z1    = 174010368;                // 32768
    const size_t OFF_Z2    = 174043136;                // 16384
    const size_t TOTAL     = 174059520;
    if (ws_size < TOTAL) return;

    char* ws = (char*)d_ws;
    float* xcat  = (float*)(ws + OFF_XCAT);
    float* uv    = (float*)(ws + OFF_UV);
    float* ymax  = (float*)(ws + OFF_YMAX);
    float* ymin  = (float*)(ws + OFF_YMIN);
    float* dist  = (float*)(ws + OFF_DIST);
    float* hraw  = (float*)(ws + OFF_DIST);   // alias, used after edge layers
    ushort* A2   = (ushort*)(ws + OFF_UV);    // alias (48MB over uv+ymax+ymin)
    ushort* B2   = (ushort*)(ws + OFF_YMIN);  // alias (3MB, inside ymin region end)
    int*   idx   = (int*)  (ws + OFF_IDX);
    float* xx    = (float*)(ws + OFF_XX);
    float* W2    = (float*)(ws + OFF_W2);
    float* bias2 = (float*)(ws + OFF_BIAS2);
    double* part = (double*)(ws + OFF_PART);
    float* scale = (float*)(ws + OFF_SCALE);
    float* shift = (float*)(ws + OFF_SHIFT);
    float* pooled= (float*)(ws + OFF_POOL);
    float* z1    = (float*)(ws + OFF_Z1);
    float* z2    = (float*)(ws + OFF_Z2);

    const int Cs[4]   = {3, 64, 64, 128};
    const int Os[4]   = {64, 64, 128, 256};
    const int offs[4] = {0, 64, 128, 256};

    for (int L = 0; L < 4; L++) {
        int C = Cs[L], O = Os[L];
        const float* w  = (const float*)d_in[1 + 4 * L];
        const float* b  = (const float*)d_in[2 + 4 * L];
        const float* g  = (const float*)d_in[3 + 4 * L];
        const float* bt = (const float*)d_in[4 + 4 * L];
        const float* x  = (L == 0) ? cloud : (xcat + offs[L - 1]);
        int lda = (L == 0) ? 3 : 512;

        prep_w2<<<(2 * O * C + 255) / 256, 256, 0, stream>>>(w, b, W2, bias2, O, C);
        sqnorm<<<(P_ + 255) / 256, 256, 0, stream>>>(x, lda, C, xx);
        dist_kernel<<<dim3(16, 16, 16), 256, 0, stream>>>(x, lda, C, xx, dist);
        topk_kernel<<<(P_ * 64) / 256, 256, 0, stream>>>(dist, idx);
        gemm_wt<<<dim3(2 * O / 64, P_ / 64), 256, 0, stream>>>(x, lda, W2, C, bias2, uv, 2 * O, C);
        gather_stats<<<1024, 256, 0, stream>>>(uv, idx, O, ymax, ymin, part, 16);
        finalize_stats<<<O / 64, 256, 0, stream>>>(part, 1024, O, g, bt, scale, shift, 1.0 / ((double)P_ * KNN));
        apply_edge<<<(P_ * O + 255) / 256, 256, 0, stream>>>(ymax, ymin, scale, shift, xcat, O, offs[L]);
    }

    // final 1x1 conv via bf16 hi/lo-split MFMA GEMM (bias cancels in BN)
    convert_a2<<<8192, 256, 0, stream>>>(xcat, A2);
    convert_b2<<<512, 256, 0, stream>>>(wf, B2);
    gemm_bf16<<<dim3(8, 128), 256, 0, stream>>>(A2, B2, hraw);

    colstats<<<256, 256, 0, stream>>>(hraw, 1024, 64, part);
    finalize_stats<<<16, 256, 0, stream>>>(part, 256, 1024, gf, btf, scale, shift, 1.0 / (double)P_);
    pool_kernel<<<dim3(16, 16), 256, 0, stream>>>(hraw, scale, shift, pooled);

    // MLP head
    fc_kernel<<<(16 * 512 * 64) / 256, 256, 0, stream>>>(pooled, 2048, wl1, 2048, bl1, z1, 16, 512, 2048);
    bn_rows<<<2, 256, 0, stream>>>(z1, 16, 512, gl1, btl1);
    fc_kernel<<<(16 * 256 * 64) / 256, 256, 0, stream>>>(z1, 512, wl2, 512, bl2, z2, 16, 256, 512);
    bn_rows<<<1, 256, 0, stream>>>(z2, 16, 256, gl2, btl2);
    fc_kernel<<<(16 * 40 * 64 + 255) / 256, 256, 0, stream>>>(z2, 256, wl3, 256, bl3, (float*)d_out, 16, 40, 256);
}

// Round 4
// 1322.703 us; speedup vs baseline: 1.3379x; 1.0016x over previous
//
#include <hip/hip_runtime.h>

#define LEAKY(v) ((v) >= 0.f ? (v) : 0.2f*(v))

static const int B_ = 16;
static const int N_ = 1024;
static const int P_ = 16384;   // B*N
static const int KNN = 20;

typedef __attribute__((ext_vector_type(8))) short short8v;
typedef __attribute__((ext_vector_type(4))) float f32x4;

__device__ inline ushort f2bf(float f) {
    unsigned u = __float_as_uint(f);
    unsigned r = u + 0x7FFFu + ((u >> 16) & 1u);
    return (ushort)(r >> 16);
}
__device__ inline float bf2f(ushort h) {
    return __uint_as_float(((unsigned)h) << 16);
}

// ---------------- prep: W2 = [wA ; wB - wA] (bias cancels in BN) ------------
__global__ void prep_w2(const float* __restrict__ w, float* __restrict__ W2, int O, int C) {
    int i = blockIdx.x * 256 + threadIdx.x;
    int total = 2 * O * C;
    if (i < total) {
        int row = i / C, c = i % C;
        float val;
        if (row < O) val = w[row * 2 * C + c];
        else { int o = row - O; val = w[o * 2 * C + C + c] - w[o * 2 * C + c]; }
        W2[i] = val;
    }
}

// ---------------- squared norms ----------------
__global__ void sqnorm(const float* __restrict__ x, int lda, int C, float* __restrict__ xx) {
    int p = blockIdx.x * 256 + threadIdx.x;
    if (p < P_) {
        const float* r = x + (size_t)p * lda;
        float s = 0.f;
        for (int c = 0; c < C; c++) s += r[c] * r[c];
        xx[p] = s;
    }
}

// ---------------- fp32 -> split-bf16 rows. mode0: [h|h|l], mode1: [h|l|h] ---
__global__ void conv_split(const float* __restrict__ src, int ld, int C, int rows,
                           ushort* __restrict__ dst, int mode) {
    int i = blockIdx.x * 256 + threadIdx.x;
    int cpr = C >> 2;
    if (i >= rows * cpr) return;
    int p = i / cpr, c4 = (i % cpr) * 4;
    float4 v = *(const float4*)(src + (size_t)p * ld + c4);
    ushort4 h, l;
    h.x = f2bf(v.x); l.x = f2bf(v.x - bf2f(h.x));
    h.y = f2bf(v.y); l.y = f2bf(v.y - bf2f(h.y));
    h.z = f2bf(v.z); l.z = f2bf(v.z - bf2f(h.z));
    h.w = f2bf(v.w); l.w = f2bf(v.w - bf2f(h.w));
    ushort* row = dst + (size_t)p * 3 * C + c4;
    if (mode == 0) {
        *(ushort4*)(row)         = h;
        *(ushort4*)(row + C)     = h;
        *(ushort4*)(row + 2 * C) = l;
    } else {
        *(ushort4*)(row)         = h;
        *(ushort4*)(row + C)     = l;
        *(ushort4*)(row + 2 * C) = h;
    }
}

// ---------------- fp32 dist (all layers): 2*dot - xx_n - xx_m ---------------
// Symmetric: blocks with m0 < n0 exit; upper blocks mirror-write both halves.
__global__ void dist_kernel(const float* __restrict__ x, int lda, int C,
                            const float* __restrict__ xx, float* __restrict__ dist) {
    int n0 = blockIdx.y * 64, m0 = blockIdx.x * 64;
    if (m0 < n0) return;
    __shared__ float As[16][68];
    __shared__ float Bs[16][68];
    int b = blockIdx.z;
    const float* xb = x + (size_t)b * N_ * lda;
    int tid = threadIdx.x;
    int tx = tid & 15, ty = tid >> 4;
    float acc[4][4] = {};
    for (int k0 = 0; k0 < C; k0 += 16) {
        for (int l = tid; l < 1024; l += 256) {
            int r = l >> 4, kk = l & 15, kg = k0 + kk;
            As[kk][r] = (kg < C) ? xb[(size_t)(n0 + r) * lda + kg] : 0.f;
            Bs[kk][r] = (kg < C) ? xb[(size_t)(m0 + r) * lda + kg] : 0.f;
        }
        __syncthreads();
        #pragma unroll
        for (int kk = 0; kk < 16; kk++) {
            float4 a4 = *(const float4*)&As[kk][ty * 4];
            float4 w4 = *(const float4*)&Bs[kk][tx * 4];
            float a[4] = {a4.x, a4.y, a4.z, a4.w};
            float w[4] = {w4.x, w4.y, w4.z, w4.w};
            #pragma unroll
            for (int i = 0; i < 4; i++)
                #pragma unroll
                for (int j = 0; j < 4; j++) acc[i][j] += a[i] * w[j];
        }
        __syncthreads();
    }
    size_t prow = (size_t)b * N_;
    for (int i = 0; i < 4; i++) {
        int n = n0 + ty * 4 + i;
        float xn = xx[b * N_ + n];
        for (int j = 0; j < 4; j++) {
            int m = m0 + tx * 4 + j;
            float v = 2.f * acc[i][j] - xn - xx[b * N_ + m];
            dist[(prow + n) * N_ + m] = v;
            dist[(prow + m) * N_ + n] = v;
        }
    }
}

// ---------------- top-k=20 (largest) per row; one wave per row --------------
__global__ void topk_kernel(const float* __restrict__ dist, int* __restrict__ idx) {
    int wave = (blockIdx.x * 256 + threadIdx.x) >> 6;
    int lane = threadIdx.x & 63;
    if (wave >= P_) return;
    const float* row = dist + (size_t)wave * N_;
    float d[16];
    #pragma unroll
    for (int j = 0; j < 16; j++) d[j] = row[j * 64 + lane];
    int* out = idx + (size_t)wave * KNN;
    for (int it = 0; it < KNN; it++) {
        float bv = d[0]; int bj = 0;
        #pragma unroll
        for (int j = 1; j < 16; j++) if (d[j] > bv) { bv = d[j]; bj = j; }
        int bm = bj * 64 + lane;
        #pragma unroll
        for (int off = 32; off > 0; off >>= 1) {
            float ov = __shfl_xor(bv, off, 64);
            int   om = __shfl_xor(bm, off, 64);
            if (ov > bv || (ov == bv && om < bm)) { bv = ov; bm = om; }
        }
        if (lane == 0) out[it] = bm;
        if ((bm & 63) == lane) d[bm >> 6] = -3.4e38f;
    }
}

// ---------------- fp32 GEMM (layer-1 uv only, K=3) --------------------------
__global__ void gemm_wt(const float* __restrict__ A, int lda,
                        const float* __restrict__ W, int ldw,
                        float* __restrict__ out, int ldo, int K) {
    __shared__ float As[16][68];
    __shared__ float Ws[16][68];
    int m0 = blockIdx.y * 64, n0 = blockIdx.x * 64;
    int tid = threadIdx.x;
    int tx = tid & 15, ty = tid >> 4;
    float acc[4][4] = {};
    for (int k0 = 0; k0 < K; k0 += 16) {
        for (int l = tid; l < 1024; l += 256) {
            int r = l >> 4, kk = l & 15, kg = k0 + kk;
            As[kk][r] = (kg < K) ? A[(size_t)(m0 + r) * lda + kg] : 0.f;
            Ws[kk][r] = (kg < K) ? W[(size_t)(n0 + r) * ldw + kg] : 0.f;
        }
        __syncthreads();
        #pragma unroll
        for (int kk = 0; kk < 16; kk++) {
            float4 a4 = *(const float4*)&As[kk][ty * 4];
            float4 w4 = *(const float4*)&Ws[kk][tx * 4];
            float a[4] = {a4.x, a4.y, a4.z, a4.w};
            float w[4] = {w4.x, w4.y, w4.z, w4.w};
            #pragma unroll
            for (int i = 0; i < 4; i++)
                #pragma unroll
                for (int j = 0; j < 4; j++) acc[i][j] += a[i] * w[j];
        }
        __syncthreads();
    }
    for (int i = 0; i < 4; i++) {
        int m = m0 + ty * 4 + i;
        for (int j = 0; j < 4; j++) {
            int n = n0 + tx * 4 + j;
            out[(size_t)m * ldo + n] = acc[i][j];
        }
    }
}

// ---------------- unified split-bf16 MFMA GEMM ------------------------------
// 128x128 tile, BK=64, 4 waves (2x2), 16x16x32 MFMA, XOR-swizzled LDS.
// MODE 0: uv    — out[m*ldo+n] = acc
// MODE 2: final — out store + per-block column sum/sumsq partials
template<int MODE>
__global__ __launch_bounds__(256, 2)
void gemm_mfma(const ushort* __restrict__ A, const ushort* __restrict__ Bw,
               int K, int nkt, float* __restrict__ out, int ldo,
               float* __restrict__ part) {
    __shared__ ushort lA[128 * 64];
    __shared__ ushort lB[128 * 64];
    int tid = threadIdx.x;
    int lane = tid & 63;
    int wid = tid >> 6;
    int wr = wid >> 1, wc = wid & 1;
    int m0 = blockIdx.y * 128, n0 = blockIdx.x * 128;

    const ushort* pA = A + (size_t)m0 * K;
    const ushort* pB = Bw + (size_t)n0 * K;
    int rowu = tid >> 3, kcu = (tid & 7) * 8;

    f32x4 acc[4][4] = {};
    short8v ra[4], rb[4];
    #pragma unroll
    for (int j = 0; j < 4; j++) {
        int row = rowu + j * 32;
        ra[j] = *(const short8v*)(pA + (size_t)row * K + kcu);
        rb[j] = *(const short8v*)(pB + (size_t)row * K + kcu);
    }

    for (int kt = 0; kt < nkt; kt++) {
        __syncthreads();
        #pragma unroll
        for (int j = 0; j < 4; j++) {
            int row = rowu + j * 32;
            int off = (row * 128 + kcu * 2) ^ ((row & 7) << 4);
            *(short8v*)((char*)lA + off) = ra[j];
            *(short8v*)((char*)lB + off) = rb[j];
        }
        __syncthreads();
        if (kt < nkt - 1) {
            int kbase = (kt + 1) * 64 + kcu;
            #pragma unroll
            for (int j = 0; j < 4; j++) {
                int row = rowu + j * 32;
                ra[j] = *(const short8v*)(pA + (size_t)row * K + kbase);
                rb[j] = *(const short8v*)(pB + (size_t)row * K + kbase);
            }
        }
        #pragma unroll
        for (int ks = 0; ks < 2; ks++) {
            short8v af[4], bg[4];
            int kb2 = (ks * 32 + ((lane >> 4) << 3)) * 2;
            #pragma unroll
            for (int mb = 0; mb < 4; mb++) {
                int row = wr * 64 + mb * 16 + (lane & 15);
                int off = (row * 128 + kb2) ^ ((row & 7) << 4);
                af[mb] = *(const short8v*)((const char*)lA + off);
            }
            #pragma unroll
            for (int nb = 0; nb < 4; nb++) {
                int row = wc * 64 + nb * 16 + (lane & 15);
                int off = (row * 128 + kb2) ^ ((row & 7) << 4);
                bg[nb] = *(const short8v*)((const char*)lB + off);
            }
            #pragma unroll
            for (int mb = 0; mb < 4; mb++)
                #pragma unroll
                for (int nb = 0; nb < 4; nb++)
                    acc[mb][nb] = __builtin_amdgcn_mfma_f32_16x16x32_bf16(af[mb], bg[nb], acc[mb][nb], 0, 0, 0);
        }
    }

    int rbase = m0 + wr * 64 + ((lane >> 4) << 2);
    int cbase = n0 + wc * 64 + (lane & 15);

    if (MODE == 0) {
        #pragma unroll
        for (int mb = 0; mb < 4; mb++)
            #pragma unroll
            for (int nb = 0; nb < 4; nb++)
                #pragma unroll
                for (int r = 0; r < 4; r++)
                    out[(size_t)(rbase + mb * 16 + r) * ldo + cbase + nb * 16] = acc[mb][nb][r];
    } else {
        float* smS = (float*)lA;
        float* smQ = (float*)lB;
        __syncthreads();   // LDS reads of main loop done; safe to reuse
        #pragma unroll
        for (int nb = 0; nb < 4; nb++) {
            float s = 0.f, q = 0.f;
            #pragma unroll
            for (int mb = 0; mb < 4; mb++)
                #pragma unroll
                for (int r = 0; r < 4; r++) {
                    float v = acc[mb][nb][r];
                    out[(size_t)(rbase + mb * 16 + r) * ldo + cbase + nb * 16] = v;
                    s += v; q += v * v;
                }
            s += __shfl_xor(s, 16, 64); s += __shfl_xor(s, 32, 64);
            q += __shfl_xor(q, 16, 64); q += __shfl_xor(q, 32, 64);
            if ((lane >> 4) == 0) {
                smS[wid * 64 + nb * 16 + lane] = s;
                smQ[wid * 64 + nb * 16 + lane] = q;
            }
        }
        __syncthreads();
        if (tid < 128) {
            int wcs = tid >> 6, c = tid & 63;
            float s = smS[wcs * 64 + c] + smS[(2 + wcs) * 64 + c];
            float q = smQ[wcs * 64 + c] + smQ[(2 + wcs) * 64 + c];
            int col = n0 + wcs * 64 + c;
            part[(size_t)blockIdx.y * 1024 + col] = s;
            part[128 * 1024 + (size_t)blockIdx.y * 1024 + col] = q;
        }
    }
}

// ---------------- gather neighbors, per-(p,o) max/min, per-channel stats ----
__global__ void gather_stats(const float* __restrict__ uv, const int* __restrict__ idx, int O,
                             float* __restrict__ ymax, float* __restrict__ ymin,
                             double* __restrict__ part, int ppb) {
    __shared__ double sd[256], sd2[256];
    int t = threadIdx.x;
    int R = 256 / O;
    int o = t % O;
    int q = t / O;
    double s = 0.0, s2 = 0.0;
    int p0 = blockIdx.x * ppb;
    int ld = 2 * O;
    for (int lp = q; lp < ppb; lp += R) {
        int p = p0 + lp;
        int b = p >> 10;
        const int* ir = idx + (size_t)p * KNN;
        float v = uv[(size_t)p * ld + O + o];
        float mx = -3.4e38f, mn = 3.4e38f;
        for (int kk = 0; kk < KNN; kk++) {
            int j = ir[kk];
            float u = uv[((size_t)((b << 10) + j)) * ld + o];
            float y = u + v;
            mx = fmaxf(mx, y); mn = fminf(mn, y);
            s += (double)y; s2 += (double)y * (double)y;
        }
        ymax[(size_t)p * O + o] = mx;
        ymin[(size_t)p * O + o] = mn;
    }
    sd[t] = s; sd2[t] = s2;
    __syncthreads();
    if (t < O) {
        double a = 0.0, a2 = 0.0;
        for (int qq = 0; qq < R; qq++) { a += sd[qq * O + t]; a2 += sd2[qq * O + t]; }
        part[(size_t)blockIdx.x * O + t] = a;
        part[(size_t)gridDim.x * O + (size_t)blockIdx.x * O + t] = a2;
    }
}

// ---------------- reduce double partials -> scale/shift ---------------------
__global__ void finalize_stats(const double* __restrict__ part, int NB, int O,
                               const float* __restrict__ g, const float* __restrict__ bt,
                               float* __restrict__ scale, float* __restrict__ shift, double invCount) {
    __shared__ double sa[256], sb2[256];
    int t = threadIdx.x;
    int o = blockIdx.x * 64 + (t & 63);
    int q = t >> 6;
    double s = 0.0, s2 = 0.0;
    for (int b = q; b < NB; b += 4) {
        s  += part[(size_t)b * O + o];
        s2 += part[(size_t)NB * O + (size_t)b * O + o];
    }
    sa[t] = s; sb2[t] = s2;
    __syncthreads();
    if (t < 64) {
        for (int c = 1; c < 4; c++) { s += sa[c * 64 + t]; s2 += sb2[c * 64 + t]; }
        double mean = s * invCount;
        double var = s2 * invCount - mean * mean;
        if (var < 0.0) var = 0.0;
        float sc = (float)(1.0 / sqrt(var + 1e-5)) * g[o];
        scale[o] = sc;
        shift[o] = bt[o] - (float)mean * sc;
    }
}

// ---------------- reduce float partials -> scale/shift ----------------------
__global__ void finalize_statsf(const float* __restrict__ part, int NB, int O,
                                const float* __restrict__ g, const float* __restrict__ bt,
                                float* __restrict__ scale, float* __restrict__ shift, double invCount) {
    __shared__ double sa[256], sb2[256];
    int t = threadIdx.x;
    int o = blockIdx.x * 64 + (t & 63);
    int q = t >> 6;
    double s = 0.0, s2 = 0.0;
    for (int b = q; b < NB; b += 4) {
        s  += (double)part[(size_t)b * O + o];
        s2 += (double)part[(size_t)NB * O + (size_t)b * O + o];
    }
    sa[t] = s; sb2[t] = s2;
    __syncthreads();
    if (t < 64) {
        for (int c = 1; c < 4; c++) { s += sa[c * 64 + t]; s2 += sb2[c * 64 + t]; }
        double mean = s * invCount;
        double var = s2 * invCount - mean * mean;
        if (var < 0.0) var = 0.0;
        float sc = (float)(1.0 / sqrt(var + 1e-5)) * g[o];
        scale[o] = sc;
        shift[o] = bt[o] - (float)mean * sc;
    }
}

// ---------------- edge conv epilogue: BN + leaky (max over k done) ----------
__global__ void apply_edge(const float* __restrict__ ymax, const float* __restrict__ ymin,
                           const float* __restrict__ scale, const float* __restrict__ shift,
                           float* __restrict__ xcat, int O, int off) {
    int i = blockIdx.x * 256 + threadIdx.x;
    if (i < P_ * O) {
        int p = i / O, o = i % O;
        float sc = scale[o];
        float y = (sc >= 0.f) ? ymax[i] : ymin[i];
        float val = y * sc + shift[o];
        xcat[(size_t)p * 512 + off + o] = LEAKY(val);
    }
}

// ---------------- global max+mean pool with fused BN+leaky ------------------
__global__ void pool_kernel(const float* __restrict__ h, const float* __restrict__ scale,
                            const float* __restrict__ shift, float* __restrict__ pooled) {
    __shared__ float smax[256];
    __shared__ double ssum[256];
    int b = blockIdx.x, og = blockIdx.y;
    int t = threadIdx.x;
    int o = og * 64 + (t & 63);
    int ch = t >> 6;
    float sc = scale[o], sh = shift[o];
    float mx = -3.4e38f;
    double sm = 0.0;
    for (int n = ch * 256; n < ch * 256 + 256; n++) {
        float y = h[((size_t)b * N_ + n) * 1024 + o] * sc + sh;
        y = LEAKY(y);
        mx = fmaxf(mx, y);
        sm += (double)y;
    }
    smax[t] = mx; ssum[t] = sm;
    __syncthreads();
    if (t < 64) {
        for (int c = 1; c < 4; c++) { mx = fmaxf(mx, smax[c * 64 + t]); sm += ssum[c * 64 + t]; }
        pooled[(size_t)b * 2048 + o] = mx;
        pooled[(size_t)b * 2048 + 1024 + o] = (float)(sm * (1.0 / N_));
    }
}

// ---------------- small FC: one wave per output -----------------------------
__global__ void fc_kernel(const float* __restrict__ in, int ldi,
                          const float* __restrict__ w, int ldw,
                          const float* __restrict__ bias,
                          float* __restrict__ out, int M, int Nn, int K) {
    int gw = (blockIdx.x * 256 + threadIdx.x) >> 6;
    int lane = threadIdx.x & 63;
    if (gw >= M * Nn) return;
    int m = gw / Nn, n = gw % Nn;
    const float* a = in + (size_t)m * ldi;
    const float* ww = w + (size_t)n * ldw;
    float s = 0.f;
    for (int kk = lane; kk < K; kk += 64) s += a[kk] * ww[kk];
    #pragma unroll
    for (int off = 32; off > 0; off >>= 1) s += __shfl_xor(s, off, 64);
    if (lane == 0) out[(size_t)m * Nn + n] = s + bias[n];
}

// ---------------- BN over batch axis (M=16) + leaky, in place ---------------
__global__ void bn_rows(float* __restrict__ z, int M, int O,
                        const float* __restrict__ g, const float* __restrict__ bt) {
    int o = blockIdx.x * 256 + threadIdx.x;
    if (o >= O) return;
    double s = 0.0, s2 = 0.0;
    for (int m = 0; m < M; m++) {
        float y = z[(size_t)m * O + o];
        s += (double)y; s2 += (double)y * (double)y;
    }
    double mean = s / M;
    double var = s2 / M - mean * mean;
    if (var < 0.0) var = 0.0;
    float sc = (float)(1.0 / sqrt(var + 1e-5)) * g[o];
    float sh = bt[o] - (float)mean * sc;
    for (int m = 0; m < M; m++) {
        float y = z[(size_t)m * O + o] * sc + sh;
        z[(size_t)m * O + o] = LEAKY(y);
    }
}

extern "C" void kernel_launch(void* const* d_in, const int* in_sizes, int n_in,
                              void* d_out, int out_size, void* d_ws, size_t ws_size,
                              hipStream_t stream) {
    const float* cloud = (const float*)d_in[0];
    const float* wf  = (const float*)d_in[17];
    const float* gf  = (const float*)d_in[19];
    const float* btf = (const float*)d_in[20];
    const float* wl1 = (const float*)d_in[21];
    const float* bl1 = (const float*)d_in[22];
    const float* gl1 = (const float*)d_in[23];
    const float* btl1= (const float*)d_in[24];
    const float* wl2 = (const float*)d_in[25];
    const float* bl2 = (const float*)d_in[26];
    const float* gl2 = (const float*)d_in[27];
    const float* btl2= (const float*)d_in[28];
    const float* wl3 = (const float*)d_in[29];
    const float* bl3 = (const float*)d_in[30];

    // workspace layout (bytes)
    const size_t OFF_XCAT  = 0;                        // 33554432
    const size_t OFF_UV    = 33554432;                 // 33554432 (A2 aliases UV+YMAX)
    const size_t OFF_YMAX  = 67108864;                 // 16777216 (xA alias: may span into YMIN, max 25.2MB, dead before ymax/ymin writes)
    const size_t OFF_YMIN  = 83886080;                 // 16777216 (B2 alias)
    const size_t OFF_DIST  = 100663296;                // 67108864 (aliased as hraw)
    const size_t OFF_IDX   = 167772160;                // 1310720
    const size_t OFF_XX    = 169082880;                // 65536
    const size_t OFF_W2    = 169148416;                // 524288
    const size_t OFF_PART  = 169676800;                // 4194304 (WB2 aliases head, dead before gather writes part)
    const size_t OFF_SCALE = 173871104;                // 4096
    const size_t OFF_SHIFT = 173875200;                // 4096
    const size_t OFF_POOL  = 173879296;                // 131072
    const size_t OFF_Z1    = 174010368;                // 32768
    const size_t OFF_Z2    = 174043136;                // 16384
    const size_t TOTAL     = 174059520;
    if (ws_size < TOTAL) return;

    char* ws = (char*)d_ws;
    float* xcat  = (float*)(ws + OFF_XCAT);
    float* uv    = (float*)(ws + OFF_UV);
    float* ymax  = (float*)(ws + OFF_YMAX);
    float* ymin  = (float*)(ws + OFF_YMIN);
    float* dist  = (float*)(ws + OFF_DIST);
    float* hraw  = (float*)(ws + OFF_DIST);
    ushort* A2   = (ushort*)(ws + OFF_UV);     // final conv A: 48MB over UV+YMAX (exactly ends at YMIN)
    ushort* B2   = (ushort*)(ws + OFF_YMIN);   // final conv B: 3MB
    ushort* xA   = (ushort*)(ws + OFF_YMAX);   // per-layer split A: up to 25.2MB, spans YMAX+YMIN
    ushort* WB2  = (ushort*)(ws + OFF_PART);   // per-layer split of W2: <0.5MB
    int*   idx   = (int*)  (ws + OFF_IDX);
    float* xx    = (float*)(ws + OFF_XX);
    float* W2    = (float*)(ws + OFF_W2);
    double* part = (double*)(ws + OFF_PART);
    float* partf = (float*)(ws + OFF_PART);
    float* scale = (float*)(ws + OFF_SCALE);
    float* shift = (float*)(ws + OFF_SHIFT);
    float* pooled= (float*)(ws + OFF_POOL);
    float* z1    = (float*)(ws + OFF_Z1);
    float* z2    = (float*)(ws + OFF_Z2);

    const int Cs[4]   = {3, 64, 64, 128};
    const int Os[4]   = {64, 64, 128, 256};
    const int offs[4] = {0, 64, 128, 256};

    for (int L = 0; L < 4; L++) {
        int C = Cs[L], O = Os[L];
        const float* w  = (const float*)d_in[1 + 4 * L];
        const float* g  = (const float*)d_in[3 + 4 * L];
        const float* bt = (const float*)d_in[4 + 4 * L];
        const float* x  = (L == 0) ? cloud : (xcat + offs[L - 1]);
        int lda = (L == 0) ? 3 : 512;

        prep_w2<<<(2 * O * C + 255) / 256, 256, 0, stream>>>(w, W2, O, C);
        sqnorm<<<(P_ + 255) / 256, 256, 0, stream>>>(x, lda, C, xx);
        dist_kernel<<<dim3(16, 16, 16), 256, 0, stream>>>(x, lda, C, xx, dist);
        topk_kernel<<<(P_ * 64) / 256, 256, 0, stream>>>(dist, idx);

        if (L == 0) {
            gemm_wt<<<dim3(2 * O / 64, P_ / 64), 256, 0, stream>>>(x, lda, W2, C, uv, 2 * O, C);
        } else {
            int K3 = 3 * C, nkt = K3 / 64;
            conv_split<<<(P_ * (C / 4) + 255) / 256, 256, 0, stream>>>(x, lda, C, P_, xA, 0);
            conv_split<<<(2 * O * (C / 4) + 255) / 256, 256, 0, stream>>>(W2, C, C, 2 * O, WB2, 1);
            gemm_mfma<0><<<dim3(2 * O / 128, 128), 256, 0, stream>>>(xA, WB2, K3, nkt, uv, 2 * O, nullptr);
        }

        gather_stats<<<1024, 256, 0, stream>>>(uv, idx, O, ymax, ymin, part, 16);
        finalize_stats<<<O / 64, 256, 0, stream>>>(part, 1024, O, g, bt, scale, shift, 1.0 / ((double)P_ * KNN));
        apply_edge<<<(P_ * O + 255) / 256, 256, 0, stream>>>(ymax, ymin, scale, shift, xcat, O, offs[L]);
    }

    // final 1x1 conv via split-bf16 MFMA GEMM with fused column stats
    conv_split<<<(P_ * 128 + 255) / 256, 256, 0, stream>>>(xcat, 512, 512, P_, A2, 0);
    conv_split<<<(1024 * 128 + 255) / 256, 256, 0, stream>>>(wf, 512, 512, 1024, B2, 1);
    gemm_mfma<2><<<dim3(8, 128), 256, 0, stream>>>(A2, B2, 1536, 24, hraw, 1024, partf);

    finalize_statsf<<<16, 256, 0, stream>>>(partf, 128, 1024, gf, btf, scale, shift, 1.0 / (double)P_);
    pool_kernel<<<dim3(16, 16), 256, 0, stream>>>(hraw, scale, shift, pooled);

    // MLP head
    fc_kernel<<<(16 * 512 * 64) / 256, 256, 0, stream>>>(pooled, 2048, wl1, 2048, bl1, z1, 16, 512, 2048);
    bn_rows<<<2, 256, 0, stream>>>(z1, 16, 512, gl1, btl1);
    fc_kernel<<<(16 * 256 * 64) / 256, 256, 0, stream>>>(z1, 512, wl2, 512, bl2, z2, 16, 256, 512);
    bn_rows<<<1, 256, 0, stream>>>(z2, 16, 256, gl2, btl2);
    fc_kernel<<<(16 * 40 * 64 + 255) / 256, 256, 0, stream>>>(z2, 256, wl3, 256, bl3, (float*)d_out, 16, 40, 256);
}

// Round 5
// 1209.412 us; speedup vs baseline: 1.4633x; 1.0937x over previous
//
#include <hip/hip_runtime.h>

#define LEAKY(v) ((v) >= 0.f ? (v) : 0.2f*(v))

static const int B_ = 16;
static const int N_ = 1024;
static const int P_ = 16384;   // B*N
static const int KNN = 20;

typedef __attribute__((ext_vector_type(8))) short short8v;
typedef __attribute__((ext_vector_type(4))) float f32x4;

__device__ inline ushort f2bf(float f) {
    unsigned u = __float_as_uint(f);
    unsigned r = u + 0x7FFFu + ((u >> 16) & 1u);
    return (ushort)(r >> 16);
}
__device__ inline float bf2f(ushort h) {
    return __uint_as_float(((unsigned)h) << 16);
}

// ---------------- prep: W2 = [wA ; wB - wA] (bias cancels in BN) ------------
__global__ void prep_w2(const float* __restrict__ w, float* __restrict__ W2, int O, int C) {
    int i = blockIdx.x * 256 + threadIdx.x;
    int total = 2 * O * C;
    if (i < total) {
        int row = i / C, c = i % C;
        float val;
        if (row < O) val = w[row * 2 * C + c];
        else { int o = row - O; val = w[o * 2 * C + C + c] - w[o * 2 * C + c]; }
        W2[i] = val;
    }
}

// ---------------- squared norms ----------------
__global__ void sqnorm(const float* __restrict__ x, int lda, int C, float* __restrict__ xx) {
    int p = blockIdx.x * 256 + threadIdx.x;
    if (p < P_) {
        const float* r = x + (size_t)p * lda;
        float s = 0.f;
        for (int c = 0; c < C; c++) s += r[c] * r[c];
        xx[p] = s;
    }
}

// ---------------- fp32 -> split-bf16 rows. mode0: [h|h|l], mode1: [h|l|h] ---
__global__ void conv_split(const float* __restrict__ src, int ld, int C, int rows,
                           ushort* __restrict__ dst, int mode) {
    int i = blockIdx.x * 256 + threadIdx.x;
    int cpr = C >> 2;
    if (i >= rows * cpr) return;
    int p = i / cpr, c4 = (i % cpr) * 4;
    float4 v = *(const float4*)(src + (size_t)p * ld + c4);
    ushort4 h, l;
    h.x = f2bf(v.x); l.x = f2bf(v.x - bf2f(h.x));
    h.y = f2bf(v.y); l.y = f2bf(v.y - bf2f(h.y));
    h.z = f2bf(v.z); l.z = f2bf(v.z - bf2f(h.z));
    h.w = f2bf(v.w); l.w = f2bf(v.w - bf2f(h.w));
    ushort* row = dst + (size_t)p * 3 * C + c4;
    if (mode == 0) {
        *(ushort4*)(row)         = h;
        *(ushort4*)(row + C)     = h;
        *(ushort4*)(row + 2 * C) = l;
    } else {
        *(ushort4*)(row)         = h;
        *(ushort4*)(row + C)     = l;
        *(ushort4*)(row + 2 * C) = h;
    }
}

// ---------------- fp32 dist (all layers): 2*dot - xx_n - xx_m ---------------
// Symmetric: blocks with m0 < n0 exit. Upper block stores its tile row-
// coalesced, then mirrors it through an LDS transpose so the mirror store
// is also row-coalesced float4 (the naive mirror was a 4B-scattered column
// store — R4 showed it made dist write-bound at 11% HBM).
__global__ void dist_kernel(const float* __restrict__ x, int lda, int C,
                            const float* __restrict__ xx, float* __restrict__ dist) {
    int n0 = blockIdx.y * 64, m0 = blockIdx.x * 64;
    if (m0 < n0) return;
    __shared__ float As[16][68];
    __shared__ float Bs[16][68];
    __shared__ float Ts[64][68];
    int b = blockIdx.z;
    const float* xb = x + (size_t)b * N_ * lda;
    int tid = threadIdx.x;
    int tx = tid & 15, ty = tid >> 4;
    float acc[4][4] = {};
    for (int k0 = 0; k0 < C; k0 += 16) {
        for (int l = tid; l < 1024; l += 256) {
            int r = l >> 4, kk = l & 15, kg = k0 + kk;
            As[kk][r] = (kg < C) ? xb[(size_t)(n0 + r) * lda + kg] : 0.f;
            Bs[kk][r] = (kg < C) ? xb[(size_t)(m0 + r) * lda + kg] : 0.f;
        }
        __syncthreads();
        #pragma unroll
        for (int kk = 0; kk < 16; kk++) {
            float4 a4 = *(const float4*)&As[kk][ty * 4];
            float4 w4 = *(const float4*)&Bs[kk][tx * 4];
            float a[4] = {a4.x, a4.y, a4.z, a4.w};
            float w[4] = {w4.x, w4.y, w4.z, w4.w};
            #pragma unroll
            for (int i = 0; i < 4; i++)
                #pragma unroll
                for (int j = 0; j < 4; j++) acc[i][j] += a[i] * w[j];
        }
        __syncthreads();
    }
    size_t prow = (size_t)b * N_;
    #pragma unroll
    for (int i = 0; i < 4; i++) {
        int n = n0 + ty * 4 + i;
        float xn = xx[b * N_ + n];
        float4 v4;
        float vt[4];
        #pragma unroll
        for (int j = 0; j < 4; j++) {
            int m = m0 + tx * 4 + j;
            float v = 2.f * acc[i][j] - xn - xx[b * N_ + m];
            vt[j] = v;
            Ts[tx * 4 + j][ty * 4 + i] = v;   // Ts[m - m0][n - n0]
        }
        v4.x = vt[0]; v4.y = vt[1]; v4.z = vt[2]; v4.w = vt[3];
        *(float4*)&dist[(prow + n) * N_ + m0 + tx * 4] = v4;
    }
    if (m0 != n0) {
        __syncthreads();
        #pragma unroll
        for (int i = 0; i < 4; i++) {
            int mi = ty * 4 + i;
            float4 v4 = *(const float4*)&Ts[mi][tx * 4];
            *(float4*)&dist[(prow + m0 + mi) * N_ + n0 + tx * 4] = v4;
        }
    }
}

// ---------------- top-k=20 (largest) per row; one wave per row --------------
__global__ void topk_kernel(const float* __restrict__ dist, int* __restrict__ idx) {
    int wave = (blockIdx.x * 256 + threadIdx.x) >> 6;
    int lane = threadIdx.x & 63;
    if (wave >= P_) return;
    const float* row = dist + (size_t)wave * N_;
    float d[16];
    #pragma unroll
    for (int j = 0; j < 16; j++) d[j] = row[j * 64 + lane];
    int* out = idx + (size_t)wave * KNN;
    for (int it = 0; it < KNN; it++) {
        float bv = d[0]; int bj = 0;
        #pragma unroll
        for (int j = 1; j < 16; j++) if (d[j] > bv) { bv = d[j]; bj = j; }
        int bm = bj * 64 + lane;
        #pragma unroll
        for (int off = 32; off > 0; off >>= 1) {
            float ov = __shfl_xor(bv, off, 64);
            int   om = __shfl_xor(bm, off, 64);
            if (ov > bv || (ov == bv && om < bm)) { bv = ov; bm = om; }
        }
        if (lane == 0) out[it] = bm;
        if ((bm & 63) == lane) d[bm >> 6] = -3.4e38f;
    }
}

// ---------------- fp32 GEMM (layer-1 uv only, K=3) --------------------------
__global__ void gemm_wt(const float* __restrict__ A, int lda,
                        const float* __restrict__ W, int ldw,
                        float* __restrict__ out, int ldo, int K) {
    __shared__ float As[16][68];
    __shared__ float Ws[16][68];
    int m0 = blockIdx.y * 64, n0 = blockIdx.x * 64;
    int tid = threadIdx.x;
    int tx = tid & 15, ty = tid >> 4;
    float acc[4][4] = {};
    for (int k0 = 0; k0 < K; k0 += 16) {
        for (int l = tid; l < 1024; l += 256) {
            int r = l >> 4, kk = l & 15, kg = k0 + kk;
            As[kk][r] = (kg < K) ? A[(size_t)(m0 + r) * lda + kg] : 0.f;
            Ws[kk][r] = (kg < K) ? W[(size_t)(n0 + r) * ldw + kg] : 0.f;
        }
        __syncthreads();
        #pragma unroll
        for (int kk = 0; kk < 16; kk++) {
            float4 a4 = *(const float4*)&As[kk][ty * 4];
            float4 w4 = *(const float4*)&Ws[kk][tx * 4];
            float a[4] = {a4.x, a4.y, a4.z, a4.w};
            float w[4] = {w4.x, w4.y, w4.z, w4.w};
            #pragma unroll
            for (int i = 0; i < 4; i++)
                #pragma unroll
                for (int j = 0; j < 4; j++) acc[i][j] += a[i] * w[j];
        }
        __syncthreads();
    }
    for (int i = 0; i < 4; i++) {
        int m = m0 + ty * 4 + i;
        for (int j = 0; j < 4; j++) {
            int n = n0 + tx * 4 + j;
            out[(size_t)m * ldo + n] = acc[i][j];
        }
    }
}

// ---------------- unified split-bf16 MFMA GEMM ------------------------------
// 128x128 tile, BK=64, 4 waves (2x2), 16x16x32 MFMA, XOR-swizzled LDS.
// MODE 0: uv    — out[m*ldo+n] = acc
// MODE 2: final — out store + per-block column sum/sumsq partials
template<int MODE>
__global__ __launch_bounds__(256, 2)
void gemm_mfma(const ushort* __restrict__ A, const ushort* __restrict__ Bw,
               int K, int nkt, float* __restrict__ out, int ldo,
               float* __restrict__ part) {
    __shared__ ushort lA[128 * 64];
    __shared__ ushort lB[128 * 64];
    int tid = threadIdx.x;
    int lane = tid & 63;
    int wid = tid >> 6;
    int wr = wid >> 1, wc = wid & 1;
    int m0 = blockIdx.y * 128, n0 = blockIdx.x * 128;

    const ushort* pA = A + (size_t)m0 * K;
    const ushort* pB = Bw + (size_t)n0 * K;
    int rowu = tid >> 3, kcu = (tid & 7) * 8;

    f32x4 acc[4][4] = {};
    short8v ra[4], rb[4];
    #pragma unroll
    for (int j = 0; j < 4; j++) {
        int row = rowu + j * 32;
        ra[j] = *(const short8v*)(pA + (size_t)row * K + kcu);
        rb[j] = *(const short8v*)(pB + (size_t)row * K + kcu);
    }

    for (int kt = 0; kt < nkt; kt++) {
        __syncthreads();
        #pragma unroll
        for (int j = 0; j < 4; j++) {
            int row = rowu + j * 32;
            int off = (row * 128 + kcu * 2) ^ ((row & 7) << 4);
            *(short8v*)((char*)lA + off) = ra[j];
            *(short8v*)((char*)lB + off) = rb[j];
        }
        __syncthreads();
        if (kt < nkt - 1) {
            int kbase = (kt + 1) * 64 + kcu;
            #pragma unroll
            for (int j = 0; j < 4; j++) {
                int row = rowu + j * 32;
                ra[j] = *(const short8v*)(pA + (size_t)row * K + kbase);
                rb[j] = *(const short8v*)(pB + (size_t)row * K + kbase);
            }
        }
        #pragma unroll
        for (int ks = 0; ks < 2; ks++) {
            short8v af[4], bg[4];
            int kb2 = (ks * 32 + ((lane >> 4) << 3)) * 2;
            #pragma unroll
            for (int mb = 0; mb < 4; mb++) {
                int row = wr * 64 + mb * 16 + (lane & 15);
                int off = (row * 128 + kb2) ^ ((row & 7) << 4);
                af[mb] = *(const short8v*)((const char*)lA + off);
            }
            #pragma unroll
            for (int nb = 0; nb < 4; nb++) {
                int row = wc * 64 + nb * 16 + (lane & 15);
                int off = (row * 128 + kb2) ^ ((row & 7) << 4);
                bg[nb] = *(const short8v*)((const char*)lB + off);
            }
            #pragma unroll
            for (int mb = 0; mb < 4; mb++)
                #pragma unroll
                for (int nb = 0; nb < 4; nb++)
                    acc[mb][nb] = __builtin_amdgcn_mfma_f32_16x16x32_bf16(af[mb], bg[nb], acc[mb][nb], 0, 0, 0);
        }
    }

    int rbase = m0 + wr * 64 + ((lane >> 4) << 2);
    int cbase = n0 + wc * 64 + (lane & 15);

    if (MODE == 0) {
        #pragma unroll
        for (int mb = 0; mb < 4; mb++)
            #pragma unroll
            for (int nb = 0; nb < 4; nb++)
                #pragma unroll
                for (int r = 0; r < 4; r++)
                    out[(size_t)(rbase + mb * 16 + r) * ldo + cbase + nb * 16] = acc[mb][nb][r];
    } else {
        float* smS = (float*)lA;
        float* smQ = (float*)lB;
        __syncthreads();   // LDS reads of main loop done; safe to reuse
        #pragma unroll
        for (int nb = 0; nb < 4; nb++) {
            float s = 0.f, q = 0.f;
            #pragma unroll
            for (int mb = 0; mb < 4; mb++)
                #pragma unroll
                for (int r = 0; r < 4; r++) {
                    float v = acc[mb][nb][r];
                    out[(size_t)(rbase + mb * 16 + r) * ldo + cbase + nb * 16] = v;
                    s += v; q += v * v;
                }
            s += __shfl_xor(s, 16, 64); s += __shfl_xor(s, 32, 64);
            q += __shfl_xor(q, 16, 64); q += __shfl_xor(q, 32, 64);
            if ((lane >> 4) == 0) {
                smS[wid * 64 + nb * 16 + lane] = s;
                smQ[wid * 64 + nb * 16 + lane] = q;
            }
        }
        __syncthreads();
        if (tid < 128) {
            int wcs = tid >> 6, c = tid & 63;
            float s = smS[wcs * 64 + c] + smS[(2 + wcs) * 64 + c];
            float q = smQ[wcs * 64 + c] + smQ[(2 + wcs) * 64 + c];
            int col = n0 + wcs * 64 + c;
            part[(size_t)blockIdx.y * 1024 + col] = s;
            part[128 * 1024 + (size_t)blockIdx.y * 1024 + col] = q;
        }
    }
}

// ---------------- gather neighbors, per-(p,o) max/min, per-channel stats ----
__global__ void gather_stats(const float* __restrict__ uv, const int* __restrict__ idx, int O,
                             float* __restrict__ ymax, float* __restrict__ ymin,
                             double* __restrict__ part, int ppb) {
    __shared__ double sd[256], sd2[256];
    int t = threadIdx.x;
    int R = 256 / O;
    int o = t % O;
    int q = t / O;
    double s = 0.0, s2 = 0.0;
    int p0 = blockIdx.x * ppb;
    int ld = 2 * O;
    for (int lp = q; lp < ppb; lp += R) {
        int p = p0 + lp;
        int b = p >> 10;
        const int* ir = idx + (size_t)p * KNN;
        float v = uv[(size_t)p * ld + O + o];
        float mx = -3.4e38f, mn = 3.4e38f;
        for (int kk = 0; kk < KNN; kk++) {
            int j = ir[kk];
            float u = uv[((size_t)((b << 10) + j)) * ld + o];
            float y = u + v;
            mx = fmaxf(mx, y); mn = fminf(mn, y);
            s += (double)y; s2 += (double)y * (double)y;
        }
        ymax[(size_t)p * O + o] = mx;
        ymin[(size_t)p * O + o] = mn;
    }
    sd[t] = s; sd2[t] = s2;
    __syncthreads();
    if (t < O) {
        double a = 0.0, a2 = 0.0;
        for (int qq = 0; qq < R; qq++) { a += sd[qq * O + t]; a2 += sd2[qq * O + t]; }
        part[(size_t)blockIdx.x * O + t] = a;
        part[(size_t)gridDim.x * O + (size_t)blockIdx.x * O + t] = a2;
    }
}

// ---------------- reduce double partials -> scale/shift ---------------------
__global__ void finalize_stats(const double* __restrict__ part, int NB, int O,
                               const float* __restrict__ g, const float* __restrict__ bt,
                               float* __restrict__ scale, float* __restrict__ shift, double invCount) {
    __shared__ double sa[256], sb2[256];
    int t = threadIdx.x;
    int o = blockIdx.x * 64 + (t & 63);
    int q = t >> 6;
    double s = 0.0, s2 = 0.0;
    for (int b = q; b < NB; b += 4) {
        s  += part[(size_t)b * O + o];
        s2 += part[(size_t)NB * O + (size_t)b * O + o];
    }
    sa[t] = s; sb2[t] = s2;
    __syncthreads();
    if (t < 64) {
        for (int c = 1; c < 4; c++) { s += sa[c * 64 + t]; s2 += sb2[c * 64 + t]; }
        double mean = s * invCount;
        double var = s2 * invCount - mean * mean;
        if (var < 0.0) var = 0.0;
        float sc = (float)(1.0 / sqrt(var + 1e-5)) * g[o];
        scale[o] = sc;
        shift[o] = bt[o] - (float)mean * sc;
    }
}

// ---------------- reduce float partials -> scale/shift ----------------------
__global__ void finalize_statsf(const float* __restrict__ part, int NB, int O,
                                const float* __restrict__ g, const float* __restrict__ bt,
                                float* __restrict__ scale, float* __restrict__ shift, double invCount) {
    __shared__ double sa[256], sb2[256];
    int t = threadIdx.x;
    int o = blockIdx.x * 64 + (t & 63);
    int q = t >> 6;
    double s = 0.0, s2 = 0.0;
    for (int b = q; b < NB; b += 4) {
        s  += (double)part[(size_t)b * O + o];
        s2 += (double)part[(size_t)NB * O + (size_t)b * O + o];
    }
    sa[t] = s; sb2[t] = s2;
    __syncthreads();
    if (t < 64) {
        for (int c = 1; c < 4; c++) { s += sa[c * 64 + t]; s2 += sb2[c * 64 + t]; }
        double mean = s * invCount;
        double var = s2 * invCount - mean * mean;
        if (var < 0.0) var = 0.0;
        float sc = (float)(1.0 / sqrt(var + 1e-5)) * g[o];
        scale[o] = sc;
        shift[o] = bt[o] - (float)mean * sc;
    }
}

// ---------------- edge conv epilogue: BN + leaky (max over k done) ----------
__global__ void apply_edge(const float* __restrict__ ymax, const float* __restrict__ ymin,
                           const float* __restrict__ scale, const float* __restrict__ shift,
                           float* __restrict__ xcat, int O, int off) {
    int i = blockIdx.x * 256 + threadIdx.x;
    if (i < P_ * O) {
        int p = i / O, o = i % O;
        float sc = scale[o];
        float y = (sc >= 0.f) ? ymax[i] : ymin[i];
        float val = y * sc + shift[o];
        xcat[(size_t)p * 512 + off + o] = LEAKY(val);
    }
}

// ---------------- global max+mean pool with fused BN+leaky ------------------
__global__ void pool_kernel(const float* __restrict__ h, const float* __restrict__ scale,
                            const float* __restrict__ shift, float* __restrict__ pooled) {
    __shared__ float smax[256];
    __shared__ double ssum[256];
    int b = blockIdx.x, og = blockIdx.y;
    int t = threadIdx.x;
    int o = og * 64 + (t & 63);
    int ch = t >> 6;
    float sc = scale[o], sh = shift[o];
    float mx = -3.4e38f;
    double sm = 0.0;
    for (int n = ch * 256; n < ch * 256 + 256; n++) {
        float y = h[((size_t)b * N_ + n) * 1024 + o] * sc + sh;
        y = LEAKY(y);
        mx = fmaxf(mx, y);
        sm += (double)y;
    }
    smax[t] = mx; ssum[t] = sm;
    __syncthreads();
    if (t < 64) {
        for (int c = 1; c < 4; c++) { mx = fmaxf(mx, smax[c * 64 + t]); sm += ssum[c * 64 + t]; }
        pooled[(size_t)b * 2048 + o] = mx;
        pooled[(size_t)b * 2048 + 1024 + o] = (float)(sm * (1.0 / N_));
    }
}

// ---------------- small FC: one wave per output -----------------------------
__global__ void fc_kernel(const float* __restrict__ in, int ldi,
                          const float* __restrict__ w, int ldw,
                          const float* __restrict__ bias,
                          float* __restrict__ out, int M, int Nn, int K) {
    int gw = (blockIdx.x * 256 + threadIdx.x) >> 6;
    int lane = threadIdx.x & 63;
    if (gw >= M * Nn) return;
    int m = gw / Nn, n = gw % Nn;
    const float* a = in + (size_t)m * ldi;
    const float* ww = w + (size_t)n * ldw;
    float s = 0.f;
    for (int kk = lane; kk < K; kk += 64) s += a[kk] * ww[kk];
    #pragma unroll
    for (int off = 32; off > 0; off >>= 1) s += __shfl_xor(s, off, 64);
    if (lane == 0) out[(size_t)m * Nn + n] = s + bias[n];
}

// ---------------- BN over batch axis (M=16) + leaky, in place ---------------
__global__ void bn_rows(float* __restrict__ z, int M, int O,
                        const float* __restrict__ g, const float* __restrict__ bt) {
    int o = blockIdx.x * 256 + threadIdx.x;
    if (o >= O) return;
    double s = 0.0, s2 = 0.0;
    for (int m = 0; m < M; m++) {
        float y = z[(size_t)m * O + o];
        s += (double)y; s2 += (double)y * (double)y;
    }
    double mean = s / M;
    double var = s2 / M - mean * mean;
    if (var < 0.0) var = 0.0;
    float sc = (float)(1.0 / sqrt(var + 1e-5)) * g[o];
    float sh = bt[o] - (float)mean * sc;
    for (int m = 0; m < M; m++) {
        float y = z[(size_t)m * O + o] * sc + sh;
        z[(size_t)m * O + o] = LEAKY(y);
    }
}

extern "C" void kernel_launch(void* const* d_in, const int* in_sizes, int n_in,
                              void* d_out, int out_size, void* d_ws, size_t ws_size,
                              hipStream_t stream) {
    const float* cloud = (const float*)d_in[0];
    const float* wf  = (const float*)d_in[17];
    const float* gf  = (const float*)d_in[19];
    const float* btf = (const float*)d_in[20];
    const float* wl1 = (const float*)d_in[21];
    const float* bl1 = (const float*)d_in[22];
    const float* gl1 = (const float*)d_in[23];
    const float* btl1= (const float*)d_in[24];
    const float* wl2 = (const float*)d_in[25];
    const float* bl2 = (const float*)d_in[26];
    const float* gl2 = (const float*)d_in[27];
    const float* btl2= (const float*)d_in[28];
    const float* wl3 = (const float*)d_in[29];
    const float* bl3 = (const float*)d_in[30];

    // workspace layout (bytes)
    const size_t OFF_XCAT  = 0;                        // 33554432
    const size_t OFF_UV    = 33554432;                 // 33554432 (A2 aliases UV+YMAX)
    const size_t OFF_YMAX  = 67108864;                 // 16777216 (xA alias: may span into YMIN, max 25.2MB, dead before ymax/ymin writes)
    const size_t OFF_YMIN  = 83886080;                 // 16777216 (B2 alias)
    const size_t OFF_DIST  = 100663296;                // 67108864 (aliased as hraw)
    const size_t OFF_IDX   = 167772160;                // 1310720
    const size_t OFF_XX    = 169082880;                // 65536
    const size_t OFF_W2    = 169148416;                // 524288
    const size_t OFF_PART  = 169676800;                // 4194304 (WB2 aliases head, dead before gather writes part)
    const size_t OFF_SCALE = 173871104;                // 4096
    const size_t OFF_SHIFT = 173875200;                // 4096
    const size_t OFF_POOL  = 173879296;                // 131072
    const size_t OFF_Z1    = 174010368;                // 32768
    const size_t OFF_Z2    = 174043136;                // 16384
    const size_t TOTAL     = 174059520;
    if (ws_size < TOTAL) return;

    char* ws = (char*)d_ws;
    float* xcat  = (float*)(ws + OFF_XCAT);
    float* uv    = (float*)(ws + OFF_UV);
    float* ymax  = (float*)(ws + OFF_YMAX);
    float* ymin  = (float*)(ws + OFF_YMIN);
    float* dist  = (float*)(ws + OFF_DIST);
    float* hraw  = (float*)(ws + OFF_DIST);
    ushort* A2   = (ushort*)(ws + OFF_UV);     // final conv A: 48MB over UV+YMAX (exactly ends at YMIN)
    ushort* B2   = (ushort*)(ws + OFF_YMIN);   // final conv B: 3MB
    ushort* xA   = (ushort*)(ws + OFF_YMAX);   // per-layer split A: up to 25.2MB, spans YMAX+YMIN
    ushort* WB2  = (ushort*)(ws + OFF_PART);   // per-layer split of W2: <0.5MB
    int*   idx   = (int*)  (ws + OFF_IDX);
    float* xx    = (float*)(ws + OFF_XX);
    float* W2    = (float*)(ws + OFF_W2);
    double* part = (double*)(ws + OFF_PART);
    float* partf = (float*)(ws + OFF_PART);
    float* scale = (float*)(ws + OFF_SCALE);
    float* shift = (float*)(ws + OFF_SHIFT);
    float* pooled= (float*)(ws + OFF_POOL);
    float* z1    = (float*)(ws + OFF_Z1);
    float* z2    = (float*)(ws + OFF_Z2);

    const int Cs[4]   = {3, 64, 64, 128};
    const int Os[4]   = {64, 64, 128, 256};
    const int offs[4] = {0, 64, 128, 256};

    for (int L = 0; L < 4; L++) {
        int C = Cs[L], O = Os[L];
        const float* w  = (const float*)d_in[1 + 4 * L];
        const float* g  = (const float*)d_in[3 + 4 * L];
        const float* bt = (const float*)d_in[4 + 4 * L];
        const float* x  = (L == 0) ? cloud : (xcat + offs[L - 1]);
        int lda = (L == 0) ? 3 : 512;

        prep_w2<<<(2 * O * C + 255) / 256, 256, 0, stream>>>(w, W2, O, C);
        sqnorm<<<(P_ + 255) / 256, 256, 0, stream>>>(x, lda, C, xx);
        dist_kernel<<<dim3(16, 16, 16), 256, 0, stream>>>(x, lda, C, xx, dist);
        topk_kernel<<<(P_ * 64) / 256, 256, 0, stream>>>(dist, idx);

        if (L == 0) {
            gemm_wt<<<dim3(2 * O / 64, P_ / 64), 256, 0, stream>>>(x, lda, W2, C, uv, 2 * O, C);
        } else {
            int K3 = 3 * C, nkt = K3 / 64;
            conv_split<<<(P_ * (C / 4) + 255) / 256, 256, 0, stream>>>(x, lda, C, P_, xA, 0);
            conv_split<<<(2 * O * (C / 4) + 255) / 256, 256, 0, stream>>>(W2, C, C, 2 * O, WB2, 1);
            gemm_mfma<0><<<dim3(2 * O / 128, 128), 256, 0, stream>>>(xA, WB2, K3, nkt, uv, 2 * O, nullptr);
        }

        gather_stats<<<1024, 256, 0, stream>>>(uv, idx, O, ymax, ymin, part, 16);
        finalize_stats<<<O / 64, 256, 0, stream>>>(part, 1024, O, g, bt, scale, shift, 1.0 / ((double)P_ * KNN));
        apply_edge<<<(P_ * O + 255) / 256, 256, 0, stream>>>(ymax, ymin, scale, shift, xcat, O, offs[L]);
    }

    // final 1x1 conv via split-bf16 MFMA GEMM with fused column stats
    conv_split<<<(P_ * 128 + 255) / 256, 256, 0, stream>>>(xcat, 512, 512, P_, A2, 0);
    conv_split<<<(1024 * 128 + 255) / 256, 256, 0, stream>>>(wf, 512, 512, 1024, B2, 1);
    gemm_mfma<2><<<dim3(8, 128), 256, 0, stream>>>(A2, B2, 1536, 24, hraw, 1024, partf);

    finalize_statsf<<<16, 256, 0, stream>>>(partf, 128, 1024, gf, btf, scale, shift, 1.0 / (double)P_);
    pool_kernel<<<dim3(16, 16), 256, 0, stream>>>(hraw, scale, shift, pooled);

    // MLP head
    fc_kernel<<<(16 * 512 * 64) / 256, 256, 0, stream>>>(pooled, 2048, wl1, 2048, bl1, z1, 16, 512, 2048);
    bn_rows<<<2, 256, 0, stream>>>(z1, 16, 512, gl1, btl1);
    fc_kernel<<<(16 * 256 * 64) / 256, 256, 0, stream>>>(z1, 512, wl2, 512, bl2, z2, 16, 256, 512);
    bn_rows<<<1, 256, 0, stream>>>(z2, 16, 256, gl2, btl2);
    fc_kernel<<<(16 * 40 * 64 + 255) / 256, 256, 0, stream>>>(z2, 256, wl3, 256, bl3, (float*)d_out, 16, 40, 256);
}

// Round 6
// 907.773 us; speedup vs baseline: 1.9495x; 1.3323x over previous
//
#include <hip/hip_runtime.h>

#define LEAKY(v) ((v) >= 0.f ? (v) : 0.2f*(v))

static const int B_ = 16;
static const int N_ = 1024;
static const int P_ = 16384;   // B*N
static const int KNN = 20;

typedef __attribute__((ext_vector_type(8))) short short8v;
typedef __attribute__((ext_vector_type(4))) float f32x4;

__device__ inline ushort f2bf(float f) {
    unsigned u = __float_as_uint(f);
    unsigned r = u + 0x7FFFu + ((u >> 16) & 1u);
    return (ushort)(r >> 16);
}
__device__ inline float bf2f(ushort h) {
    return __uint_as_float(((unsigned)h) << 16);
}

// ---------------- prep: W2 = [wA ; wB - wA] fp32 (layer-1 only) -------------
__global__ void prep_w2(const float* __restrict__ w, float* __restrict__ W2, int O, int C) {
    int i = blockIdx.x * 256 + threadIdx.x;
    int total = 2 * O * C;
    if (i < total) {
        int row = i / C, c = i % C;
        float val;
        if (row < O) val = w[row * 2 * C + c];
        else { int o = row - O; val = w[o * 2 * C + C + c] - w[o * 2 * C + c]; }
        W2[i] = val;
    }
}

// ---------------- prep W2 and split to bf16 [h|l|h] in one pass (L>=1) ------
__global__ void prep_w2_split(const float* __restrict__ w, ushort* __restrict__ WB2, int O, int C) {
    int i = blockIdx.x * 256 + threadIdx.x;
    int cpr = C >> 2;
    if (i >= 2 * O * cpr) return;
    int row = i / cpr, c4 = (i % cpr) * 4;
    float vv[4];
    #pragma unroll
    for (int j = 0; j < 4; j++) {
        int c = c4 + j;
        if (row < O) vv[j] = w[row * 2 * C + c];
        else { int o = row - O; vv[j] = w[o * 2 * C + C + c] - w[o * 2 * C + c]; }
    }
    ushort4 h, l;
    h.x = f2bf(vv[0]); l.x = f2bf(vv[0] - bf2f(h.x));
    h.y = f2bf(vv[1]); l.y = f2bf(vv[1] - bf2f(h.y));
    h.z = f2bf(vv[2]); l.z = f2bf(vv[2] - bf2f(h.z));
    h.w = f2bf(vv[3]); l.w = f2bf(vv[3] - bf2f(h.w));
    ushort* rowp = WB2 + (size_t)row * 3 * C + c4;
    *(ushort4*)(rowp)         = h;
    *(ushort4*)(rowp + C)     = l;
    *(ushort4*)(rowp + 2 * C) = h;
}

// ---------------- squared norms ----------------
__global__ void sqnorm(const float* __restrict__ x, int lda, int C, float* __restrict__ xx) {
    int p = blockIdx.x * 256 + threadIdx.x;
    if (p < P_) {
        const float* r = x + (size_t)p * lda;
        float s = 0.f;
        for (int c = 0; c < C; c++) s += r[c] * r[c];
        xx[p] = s;
    }
}

// ---------------- fp32 -> split-bf16 rows. mode0: [h|h|l], mode1: [h|l|h] ---
__global__ void conv_split(const float* __restrict__ src, int ld, int C, int rows,
                           ushort* __restrict__ dst, int mode) {
    int i = blockIdx.x * 256 + threadIdx.x;
    int cpr = C >> 2;
    if (i >= rows * cpr) return;
    int p = i / cpr, c4 = (i % cpr) * 4;
    float4 v = *(const float4*)(src + (size_t)p * ld + c4);
    ushort4 h, l;
    h.x = f2bf(v.x); l.x = f2bf(v.x - bf2f(h.x));
    h.y = f2bf(v.y); l.y = f2bf(v.y - bf2f(h.y));
    h.z = f2bf(v.z); l.z = f2bf(v.z - bf2f(h.z));
    h.w = f2bf(v.w); l.w = f2bf(v.w - bf2f(h.w));
    ushort* row = dst + (size_t)p * 3 * C + c4;
    if (mode == 0) {
        *(ushort4*)(row)         = h;
        *(ushort4*)(row + C)     = h;
        *(ushort4*)(row + 2 * C) = l;
    } else {
        *(ushort4*)(row)         = h;
        *(ushort4*)(row + C)     = l;
        *(ushort4*)(row + 2 * C) = h;
    }
}

// ---------------- fp32 dist (all layers): 2*dot - xx_n - xx_m ---------------
// Symmetric: m0 < n0 blocks exit; mirror store goes through an LDS transpose
// so both stores are row-coalesced float4.
__global__ void dist_kernel(const float* __restrict__ x, int lda, int C,
                            const float* __restrict__ xx, float* __restrict__ dist) {
    int n0 = blockIdx.y * 64, m0 = blockIdx.x * 64;
    if (m0 < n0) return;
    __shared__ float As[16][68];
    __shared__ float Bs[16][68];
    __shared__ float Ts[64][68];
    int b = blockIdx.z;
    const float* xb = x + (size_t)b * N_ * lda;
    int tid = threadIdx.x;
    int tx = tid & 15, ty = tid >> 4;
    float acc[4][4] = {};
    for (int k0 = 0; k0 < C; k0 += 16) {
        for (int l = tid; l < 1024; l += 256) {
            int r = l >> 4, kk = l & 15, kg = k0 + kk;
            As[kk][r] = (kg < C) ? xb[(size_t)(n0 + r) * lda + kg] : 0.f;
            Bs[kk][r] = (kg < C) ? xb[(size_t)(m0 + r) * lda + kg] : 0.f;
        }
        __syncthreads();
        #pragma unroll
        for (int kk = 0; kk < 16; kk++) {
            float4 a4 = *(const float4*)&As[kk][ty * 4];
            float4 w4 = *(const float4*)&Bs[kk][tx * 4];
            float a[4] = {a4.x, a4.y, a4.z, a4.w};
            float w[4] = {w4.x, w4.y, w4.z, w4.w};
            #pragma unroll
            for (int i = 0; i < 4; i++)
                #pragma unroll
                for (int j = 0; j < 4; j++) acc[i][j] += a[i] * w[j];
        }
        __syncthreads();
    }
    size_t prow = (size_t)b * N_;
    #pragma unroll
    for (int i = 0; i < 4; i++) {
        int n = n0 + ty * 4 + i;
        float xn = xx[b * N_ + n];
        float4 v4;
        float vt[4];
        #pragma unroll
        for (int j = 0; j < 4; j++) {
            int m = m0 + tx * 4 + j;
            float v = 2.f * acc[i][j] - xn - xx[b * N_ + m];
            vt[j] = v;
            Ts[tx * 4 + j][ty * 4 + i] = v;   // Ts[m - m0][n - n0]
        }
        v4.x = vt[0]; v4.y = vt[1]; v4.z = vt[2]; v4.w = vt[3];
        *(float4*)&dist[(prow + n) * N_ + m0 + tx * 4] = v4;
    }
    if (m0 != n0) {
        __syncthreads();
        #pragma unroll
        for (int i = 0; i < 4; i++) {
            int mi = ty * 4 + i;
            float4 v4 = *(const float4*)&Ts[mi][tx * 4];
            *(float4*)&dist[(prow + m0 + mi) * N_ + n0 + tx * 4] = v4;
        }
    }
}

// ---------------- top-k=20 (largest) per row; one wave per row --------------
__global__ void topk_kernel(const float* __restrict__ dist, int* __restrict__ idx) {
    int wave = (blockIdx.x * 256 + threadIdx.x) >> 6;
    int lane = threadIdx.x & 63;
    if (wave >= P_) return;
    const float* row = dist + (size_t)wave * N_;
    float d[16];
    #pragma unroll
    for (int j = 0; j < 16; j++) d[j] = row[j * 64 + lane];
    int* out = idx + (size_t)wave * KNN;
    for (int it = 0; it < KNN; it++) {
        float bv = d[0]; int bj = 0;
        #pragma unroll
        for (int j = 1; j < 16; j++) if (d[j] > bv) { bv = d[j]; bj = j; }
        int bm = bj * 64 + lane;
        #pragma unroll
        for (int off = 32; off > 0; off >>= 1) {
            float ov = __shfl_xor(bv, off, 64);
            int   om = __shfl_xor(bm, off, 64);
            if (ov > bv || (ov == bv && om < bm)) { bv = ov; bm = om; }
        }
        if (lane == 0) out[it] = bm;
        if ((bm & 63) == lane) d[bm >> 6] = -3.4e38f;
    }
}

// ---------------- fp32 GEMM (layer-1 uv only, K=3) --------------------------
__global__ void gemm_wt(const float* __restrict__ A, int lda,
                        const float* __restrict__ W, int ldw,
                        float* __restrict__ out, int ldo, int K) {
    __shared__ float As[16][68];
    __shared__ float Ws[16][68];
    int m0 = blockIdx.y * 64, n0 = blockIdx.x * 64;
    int tid = threadIdx.x;
    int tx = tid & 15, ty = tid >> 4;
    float acc[4][4] = {};
    for (int k0 = 0; k0 < K; k0 += 16) {
        for (int l = tid; l < 1024; l += 256) {
            int r = l >> 4, kk = l & 15, kg = k0 + kk;
            As[kk][r] = (kg < K) ? A[(size_t)(m0 + r) * lda + kg] : 0.f;
            Ws[kk][r] = (kg < K) ? W[(size_t)(n0 + r) * ldw + kg] : 0.f;
        }
        __syncthreads();
        #pragma unroll
        for (int kk = 0; kk < 16; kk++) {
            float4 a4 = *(const float4*)&As[kk][ty * 4];
            float4 w4 = *(const float4*)&Ws[kk][tx * 4];
            float a[4] = {a4.x, a4.y, a4.z, a4.w};
            float w[4] = {w4.x, w4.y, w4.z, w4.w};
            #pragma unroll
            for (int i = 0; i < 4; i++)
                #pragma unroll
                for (int j = 0; j < 4; j++) acc[i][j] += a[i] * w[j];
        }
        __syncthreads();
    }
    for (int i = 0; i < 4; i++) {
        int m = m0 + ty * 4 + i;
        for (int j = 0; j < 4; j++) {
            int n = n0 + tx * 4 + j;
            out[(size_t)m * ldo + n] = acc[i][j];
        }
    }
}

// ---------------- unified split-bf16 MFMA GEMM ------------------------------
// MODE 0: uv    — plain store
// MODE 2: final — store + per-block column sum/sumsq partials (transposed:
//                 part[col*128 + mblock]) so the finalize read is parallel.
template<int MODE>
__global__ __launch_bounds__(256, 2)
void gemm_mfma(const ushort* __restrict__ A, const ushort* __restrict__ Bw,
               int K, int nkt, float* __restrict__ out, int ldo,
               float* __restrict__ part) {
    __shared__ ushort lA[128 * 64];
    __shared__ ushort lB[128 * 64];
    int tid = threadIdx.x;
    int lane = tid & 63;
    int wid = tid >> 6;
    int wr = wid >> 1, wc = wid & 1;
    int m0 = blockIdx.y * 128, n0 = blockIdx.x * 128;

    const ushort* pA = A + (size_t)m0 * K;
    const ushort* pB = Bw + (size_t)n0 * K;
    int rowu = tid >> 3, kcu = (tid & 7) * 8;

    f32x4 acc[4][4] = {};
    short8v ra[4], rb[4];
    #pragma unroll
    for (int j = 0; j < 4; j++) {
        int row = rowu + j * 32;
        ra[j] = *(const short8v*)(pA + (size_t)row * K + kcu);
        rb[j] = *(const short8v*)(pB + (size_t)row * K + kcu);
    }

    for (int kt = 0; kt < nkt; kt++) {
        __syncthreads();
        #pragma unroll
        for (int j = 0; j < 4; j++) {
            int row = rowu + j * 32;
            int off = (row * 128 + kcu * 2) ^ ((row & 7) << 4);
            *(short8v*)((char*)lA + off) = ra[j];
            *(short8v*)((char*)lB + off) = rb[j];
        }
        __syncthreads();
        if (kt < nkt - 1) {
            int kbase = (kt + 1) * 64 + kcu;
            #pragma unroll
            for (int j = 0; j < 4; j++) {
                int row = rowu + j * 32;
                ra[j] = *(const short8v*)(pA + (size_t)row * K + kbase);
                rb[j] = *(const short8v*)(pB + (size_t)row * K + kbase);
            }
        }
        #pragma unroll
        for (int ks = 0; ks < 2; ks++) {
            short8v af[4], bg[4];
            int kb2 = (ks * 32 + ((lane >> 4) << 3)) * 2;
            #pragma unroll
            for (int mb = 0; mb < 4; mb++) {
                int row = wr * 64 + mb * 16 + (lane & 15);
                int off = (row * 128 + kb2) ^ ((row & 7) << 4);
                af[mb] = *(const short8v*)((const char*)lA + off);
            }
            #pragma unroll
            for (int nb = 0; nb < 4; nb++) {
                int row = wc * 64 + nb * 16 + (lane & 15);
                int off = (row * 128 + kb2) ^ ((row & 7) << 4);
                bg[nb] = *(const short8v*)((const char*)lB + off);
            }
            #pragma unroll
            for (int mb = 0; mb < 4; mb++)
                #pragma unroll
                for (int nb = 0; nb < 4; nb++)
                    acc[mb][nb] = __builtin_amdgcn_mfma_f32_16x16x32_bf16(af[mb], bg[nb], acc[mb][nb], 0, 0, 0);
        }
    }

    int rbase = m0 + wr * 64 + ((lane >> 4) << 2);
    int cbase = n0 + wc * 64 + (lane & 15);

    if (MODE == 0) {
        #pragma unroll
        for (int mb = 0; mb < 4; mb++)
            #pragma unroll
            for (int nb = 0; nb < 4; nb++)
                #pragma unroll
                for (int r = 0; r < 4; r++)
                    out[(size_t)(rbase + mb * 16 + r) * ldo + cbase + nb * 16] = acc[mb][nb][r];
    } else {
        float* smS = (float*)lA;
        float* smQ = (float*)lB;
        __syncthreads();   // LDS reads of main loop done; safe to reuse
        #pragma unroll
        for (int nb = 0; nb < 4; nb++) {
            float s = 0.f, q = 0.f;
            #pragma unroll
            for (int mb = 0; mb < 4; mb++)
                #pragma unroll
                for (int r = 0; r < 4; r++) {
                    float v = acc[mb][nb][r];
                    out[(size_t)(rbase + mb * 16 + r) * ldo + cbase + nb * 16] = v;
                    s += v; q += v * v;
                }
            s += __shfl_xor(s, 16, 64); s += __shfl_xor(s, 32, 64);
            q += __shfl_xor(q, 16, 64); q += __shfl_xor(q, 32, 64);
            if ((lane >> 4) == 0) {
                smS[wid * 64 + nb * 16 + lane] = s;
                smQ[wid * 64 + nb * 16 + lane] = q;
            }
        }
        __syncthreads();
        if (tid < 128) {
            int wcs = tid >> 6, c = tid & 63;
            float s = smS[wcs * 64 + c] + smS[(2 + wcs) * 64 + c];
            float q = smQ[wcs * 64 + c] + smQ[(2 + wcs) * 64 + c];
            int col = n0 + wcs * 64 + c;
            part[(size_t)col * 128 + blockIdx.y] = s;
            part[131072 + (size_t)col * 128 + blockIdx.y] = q;
        }
    }
}

// ---------------- gather neighbors, per-(p,o) max/min, per-channel stats ----
// Partials written TRANSPOSED: part[o*1024 + block], part[(O+o)*1024 + block]
__global__ void gather_stats(const float* __restrict__ uv, const int* __restrict__ idx, int O,
                             float* __restrict__ ymax, float* __restrict__ ymin,
                             double* __restrict__ part, int ppb) {
    __shared__ double sd[256], sd2[256];
    int t = threadIdx.x;
    int R = 256 / O;
    int o = t % O;
    int q = t / O;
    double s = 0.0, s2 = 0.0;
    int p0 = blockIdx.x * ppb;
    int ld = 2 * O;
    for (int lp = q; lp < ppb; lp += R) {
        int p = p0 + lp;
        int b = p >> 10;
        const int* ir = idx + (size_t)p * KNN;
        float v = uv[(size_t)p * ld + O + o];
        float mx = -3.4e38f, mn = 3.4e38f;
        for (int kk = 0; kk < KNN; kk++) {
            int j = ir[kk];
            float u = uv[((size_t)((b << 10) + j)) * ld + o];
            float y = u + v;
            mx = fmaxf(mx, y); mn = fminf(mn, y);
            s += (double)y; s2 += (double)y * (double)y;
        }
        ymax[(size_t)p * O + o] = mx;
        ymin[(size_t)p * O + o] = mn;
    }
    sd[t] = s; sd2[t] = s2;
    __syncthreads();
    if (t < O) {
        double a = 0.0, a2 = 0.0;
        for (int qq = 0; qq < R; qq++) { a += sd[qq * O + t]; a2 += sd2[qq * O + t]; }
        part[(size_t)t * 1024 + blockIdx.x] = a;
        part[(size_t)(O + t) * 1024 + blockIdx.x] = a2;
    }
}

// ---------------- parallel finalize: one block per channel ------------------
__global__ void finalize_t(const double* __restrict__ part, int O,
                           const float* __restrict__ g, const float* __restrict__ bt,
                           float* __restrict__ scale, float* __restrict__ shift, double invCount) {
    __shared__ double sa[4], sb[4];
    int o = blockIdx.x;
    int t = threadIdx.x;
    int lane = t & 63, w = t >> 6;
    const double* ps = part + (size_t)o * 1024;
    const double* pq = part + (size_t)(O + o) * 1024;
    double s = 0.0, s2 = 0.0;
    #pragma unroll
    for (int b = 0; b < 4; b++) { s += ps[t + b * 256]; s2 += pq[t + b * 256]; }
    #pragma unroll
    for (int off = 32; off > 0; off >>= 1) { s += __shfl_xor(s, off, 64); s2 += __shfl_xor(s2, off, 64); }
    if (lane == 0) { sa[w] = s; sb[w] = s2; }
    __syncthreads();
    if (t == 0) {
        s = sa[0] + sa[1] + sa[2] + sa[3];
        s2 = sb[0] + sb[1] + sb[2] + sb[3];
        double mean = s * invCount;
        double var = s2 * invCount - mean * mean;
        if (var < 0.0) var = 0.0;
        float sc = (float)(1.0 / sqrt(var + 1e-5)) * g[o];
        scale[o] = sc;
        shift[o] = bt[o] - (float)mean * sc;
    }
}

// ---------------- parallel finalize for float partials (final conv) ---------
__global__ void finalize_f_t(const float* __restrict__ part,
                             const float* __restrict__ g, const float* __restrict__ bt,
                             float* __restrict__ scale, float* __restrict__ shift, double invCount) {
    __shared__ double sa[2], sb[2];
    int o = blockIdx.x;
    int t = threadIdx.x;   // 128 threads
    int lane = t & 63, w = t >> 6;
    double s  = (double)part[(size_t)o * 128 + t];
    double s2 = (double)part[131072 + (size_t)o * 128 + t];
    #pragma unroll
    for (int off = 32; off > 0; off >>= 1) { s += __shfl_xor(s, off, 64); s2 += __shfl_xor(s2, off, 64); }
    if (lane == 0) { sa[w] = s; sb[w] = s2; }
    __syncthreads();
    if (t == 0) {
        s = sa[0] + sa[1];
        s2 = sb[0] + sb[1];
        double mean = s * invCount;
        double var = s2 * invCount - mean * mean;
        if (var < 0.0) var = 0.0;
        float sc = (float)(1.0 / sqrt(var + 1e-5)) * g[o];
        scale[o] = sc;
        shift[o] = bt[o] - (float)mean * sc;
    }
}

// ---------------- edge conv epilogue: BN + leaky (max over k done) ----------
__global__ void apply_edge(const float* __restrict__ ymax, const float* __restrict__ ymin,
                           const float* __restrict__ scale, const float* __restrict__ shift,
                           float* __restrict__ xcat, int O, int off) {
    int i = blockIdx.x * 256 + threadIdx.x;
    if (i < P_ * O) {
        int p = i / O, o = i % O;
        float sc = scale[o];
        float y = (sc >= 0.f) ? ymax[i] : ymin[i];
        float val = y * sc + shift[o];
        xcat[(size_t)p * 512 + off + o] = LEAKY(val);
    }
}

// ---------------- global max+mean pool with fused BN+leaky ------------------
__global__ void pool_kernel(const float* __restrict__ h, const float* __restrict__ scale,
                            const float* __restrict__ shift, float* __restrict__ pooled) {
    __shared__ float smax[256];
    __shared__ double ssum[256];
    int b = blockIdx.x, og = blockIdx.y;
    int t = threadIdx.x;
    int o = og * 64 + (t & 63);
    int ch = t >> 6;
    float sc = scale[o], sh = shift[o];
    float mx = -3.4e38f;
    double sm = 0.0;
    for (int n = ch * 256; n < ch * 256 + 256; n++) {
        float y = h[((size_t)b * N_ + n) * 1024 + o] * sc + sh;
        y = LEAKY(y);
        mx = fmaxf(mx, y);
        sm += (double)y;
    }
    smax[t] = mx; ssum[t] = sm;
    __syncthreads();
    if (t < 64) {
        for (int c = 1; c < 4; c++) { mx = fmaxf(mx, smax[c * 64 + t]); sm += ssum[c * 64 + t]; }
        pooled[(size_t)b * 2048 + o] = mx;
        pooled[(size_t)b * 2048 + 1024 + o] = (float)(sm * (1.0 / N_));
    }
}

// ---------------- small FC: one wave per output -----------------------------
__global__ void fc_kernel(const float* __restrict__ in, int ldi,
                          const float* __restrict__ w, int ldw,
                          const float* __restrict__ bias,
                          float* __restrict__ out, int M, int Nn, int K) {
    int gw = (blockIdx.x * 256 + threadIdx.x) >> 6;
    int lane = threadIdx.x & 63;
    if (gw >= M * Nn) return;
    int m = gw / Nn, n = gw % Nn;
    const float* a = in + (size_t)m * ldi;
    const float* ww = w + (size_t)n * ldw;
    float s = 0.f;
    for (int kk = lane; kk < K; kk += 64) s += a[kk] * ww[kk];
    #pragma unroll
    for (int off = 32; off > 0; off >>= 1) s += __shfl_xor(s, off, 64);
    if (lane == 0) out[(size_t)m * Nn + n] = s + bias[n];
}

// ---------------- BN over batch axis (M=16) + leaky, in place ---------------
__global__ void bn_rows(float* __restrict__ z, int M, int O,
                        const float* __restrict__ g, const float* __restrict__ bt) {
    int o = blockIdx.x * 256 + threadIdx.x;
    if (o >= O) return;
    double s = 0.0, s2 = 0.0;
    for (int m = 0; m < M; m++) {
        float y = z[(size_t)m * O + o];
        s += (double)y; s2 += (double)y * (double)y;
    }
    double mean = s / M;
    double var = s2 / M - mean * mean;
    if (var < 0.0) var = 0.0;
    float sc = (float)(1.0 / sqrt(var + 1e-5)) * g[o];
    float sh = bt[o] - (float)mean * sc;
    for (int m = 0; m < M; m++) {
        float y = z[(size_t)m * O + o] * sc + sh;
        z[(size_t)m * O + o] = LEAKY(y);
    }
}

extern "C" void kernel_launch(void* const* d_in, const int* in_sizes, int n_in,
                              void* d_out, int out_size, void* d_ws, size_t ws_size,
                              hipStream_t stream) {
    const float* cloud = (const float*)d_in[0];
    const float* wf  = (const float*)d_in[17];
    const float* gf  = (const float*)d_in[19];
    const float* btf = (const float*)d_in[20];
    const float* wl1 = (const float*)d_in[21];
    const float* bl1 = (const float*)d_in[22];
    const float* gl1 = (const float*)d_in[23];
    const float* btl1= (const float*)d_in[24];
    const float* wl2 = (const float*)d_in[25];
    const float* bl2 = (const float*)d_in[26];
    const float* gl2 = (const float*)d_in[27];
    const float* btl2= (const float*)d_in[28];
    const float* wl3 = (const float*)d_in[29];
    const float* bl3 = (const float*)d_in[30];

    // workspace layout (bytes)
    const size_t OFF_XCAT  = 0;                        // 33554432
    const size_t OFF_UV    = 33554432;                 // 33554432 (A2 aliases UV+YMAX)
    const size_t OFF_YMAX  = 67108864;                 // 16777216 (xA alias: spans into YMIN, max 25.2MB, dead before ymax/ymin writes)
    const size_t OFF_YMIN  = 83886080;                 // 16777216 (B2 alias)
    const size_t OFF_DIST  = 100663296;                // 67108864 (aliased as hraw)
    const size_t OFF_IDX   = 167772160;                // 1310720
    const size_t OFF_XX    = 169082880;                // 65536
    const size_t OFF_W2    = 169148416;                // 524288
    const size_t OFF_PART  = 169676800;                // 4194304: part[2*O][1024] doubles (WB2 aliases head, dead before gather)
    const size_t OFF_SCALE = 173871104;                // 4096
    const size_t OFF_SHIFT = 173875200;                // 4096
    const size_t OFF_POOL  = 173879296;                // 131072
    const size_t OFF_Z1    = 174010368;                // 32768
    const size_t OFF_Z2    = 174043136;                // 16384
    const size_t TOTAL     = 174059520;
    if (ws_size < TOTAL) return;

    char* ws = (char*)d_ws;
    float* xcat  = (float*)(ws + OFF_XCAT);
    float* uv    = (float*)(ws + OFF_UV);
    float* ymax  = (float*)(ws + OFF_YMAX);
    float* ymin  = (float*)(ws + OFF_YMIN);
    float* dist  = (float*)(ws + OFF_DIST);
    float* hraw  = (float*)(ws + OFF_DIST);
    ushort* A2   = (ushort*)(ws + OFF_UV);     // final conv A: 48MB over UV+YMAX
    ushort* B2   = (ushort*)(ws + OFF_YMIN);   // final conv B: 3MB
    ushort* xA   = (ushort*)(ws + OFF_YMAX);   // per-layer split A: up to 25.2MB
    ushort* WB2  = (ushort*)(ws + OFF_PART);   // per-layer split of W2: <0.5MB
    int*   idx   = (int*)  (ws + OFF_IDX);
    float* xx    = (float*)(ws + OFF_XX);
    float* W2    = (float*)(ws + OFF_W2);
    double* part = (double*)(ws + OFF_PART);
    float* partf = (float*)(ws + OFF_PART);
    float* scale = (float*)(ws + OFF_SCALE);
    float* shift = (float*)(ws + OFF_SHIFT);
    float* pooled= (float*)(ws + OFF_POOL);
    float* z1    = (float*)(ws + OFF_Z1);
    float* z2    = (float*)(ws + OFF_Z2);

    const int Cs[4]   = {3, 64, 64, 128};
    const int Os[4]   = {64, 64, 128, 256};
    const int offs[4] = {0, 64, 128, 256};

    for (int L = 0; L < 4; L++) {
        int C = Cs[L], O = Os[L];
        const float* w  = (const float*)d_in[1 + 4 * L];
        const float* g  = (const float*)d_in[3 + 4 * L];
        const float* bt = (const float*)d_in[4 + 4 * L];
        const float* x  = (L == 0) ? cloud : (xcat + offs[L - 1]);
        int lda = (L == 0) ? 3 : 512;

        sqnorm<<<(P_ + 255) / 256, 256, 0, stream>>>(x, lda, C, xx);
        dist_kernel<<<dim3(16, 16, 16), 256, 0, stream>>>(x, lda, C, xx, dist);
        topk_kernel<<<(P_ * 64) / 256, 256, 0, stream>>>(dist, idx);

        if (L == 0) {
            prep_w2<<<(2 * O * C + 255) / 256, 256, 0, stream>>>(w, W2, O, C);
            gemm_wt<<<dim3(2 * O / 64, P_ / 64), 256, 0, stream>>>(x, lda, W2, C, uv, 2 * O, C);
        } else {
            int K3 = 3 * C, nkt = K3 / 64;
            conv_split<<<(P_ * (C / 4) + 255) / 256, 256, 0, stream>>>(x, lda, C, P_, xA, 0);
            prep_w2_split<<<(2 * O * (C / 4) + 255) / 256, 256, 0, stream>>>(w, WB2, O, C);
            gemm_mfma<0><<<dim3(2 * O / 128, 128), 256, 0, stream>>>(xA, WB2, K3, nkt, uv, 2 * O, nullptr);
        }

        gather_stats<<<1024, 256, 0, stream>>>(uv, idx, O, ymax, ymin, part, 16);
        finalize_t<<<O, 256, 0, stream>>>(part, O, g, bt, scale, shift, 1.0 / ((double)P_ * KNN));
        apply_edge<<<(P_ * O + 255) / 256, 256, 0, stream>>>(ymax, ymin, scale, shift, xcat, O, offs[L]);
    }

    // final 1x1 conv via split-bf16 MFMA GEMM with fused (transposed) col stats
    conv_split<<<(P_ * 128 + 255) / 256, 256, 0, stream>>>(xcat, 512, 512, P_, A2, 0);
    conv_split<<<(1024 * 128 + 255) / 256, 256, 0, stream>>>(wf, 512, 512, 1024, B2, 1);
    gemm_mfma<2><<<dim3(8, 128), 256, 0, stream>>>(A2, B2, 1536, 24, hraw, 1024, partf);

    finalize_f_t<<<1024, 128, 0, stream>>>(partf, gf, btf, scale, shift, 1.0 / (double)P_);
    pool_kernel<<<dim3(16, 16), 256, 0, stream>>>(hraw, scale, shift, pooled);

    // MLP head
    fc_kernel<<<(16 * 512 * 64) / 256, 256, 0, stream>>>(pooled, 2048, wl1, 2048, bl1, z1, 16, 512, 2048);
    bn_rows<<<2, 256, 0, stream>>>(z1, 16, 512, gl1, btl1);
    fc_kernel<<<(16 * 256 * 64) / 256, 256, 0, stream>>>(z1, 512, wl2, 512, bl2, z2, 16, 256, 512);
    bn_rows<<<1, 256, 0, stream>>>(z2, 16, 256, gl2, btl2);
    fc_kernel<<<(16 * 40 * 64 + 255) / 256, 256, 0, stream>>>(z2, 256, wl3, 256, bl3, (float*)d_out, 16, 40, 256);
}